// Round 1
// baseline (13204.060 us; speedup 1.0000x reference)
//
#include <hip/hip_runtime.h>
#include <hip/hip_bf16.h>

// GCN forward: softmax( A * relu(A*(x@W1)+b1) @ W2 )
// N=100000 nodes, E=3.2M edges, F 512->256->40, all fp32.

#define NFEAT 512
#define NHID  256
#define NCLASS 40

// ---------------- gemm1: support1 = x @ W1  ([M,512]@[512,256]) ----------------
#define BM 64
#define BN 64
#define BK 16

__global__ __launch_bounds__(256) void gemm1_kernel(const float* __restrict__ A,
                                                    const float* __restrict__ W,
                                                    float* __restrict__ C,
                                                    int M) {
    __shared__ float As[BK][BM + 1];
    __shared__ float Bs[BK][BN + 1];
    const int tid = threadIdx.x;
    const int row0 = blockIdx.x * BM;
    const int col0 = blockIdx.y * BN;
    const int tr = tid / 16;          // 0..15
    const int tc = tid % 16;          // 0..15
    float acc[4][4] = {};

    for (int k0 = 0; k0 < NFEAT; k0 += BK) {
        // A tile: 64 rows x 16 k. thread -> row tid/4, k (tid%4)*4, float4
        {
            int ar = tid >> 2;
            int ak = (tid & 3) << 2;
            int gr = row0 + ar;
            float4 v = make_float4(0.f, 0.f, 0.f, 0.f);
            if (gr < M) v = *reinterpret_cast<const float4*>(&A[(size_t)gr * NFEAT + k0 + ak]);
            As[ak + 0][ar] = v.x;
            As[ak + 1][ar] = v.y;
            As[ak + 2][ar] = v.z;
            As[ak + 3][ar] = v.w;
        }
        // B tile: 16 k x 64 cols. thread -> k tid/16, col (tid%16)*4, float4
        {
            int bk = tid >> 4;
            int bc = (tid & 15) << 2;
            float4 v = *reinterpret_cast<const float4*>(&W[(size_t)(k0 + bk) * NHID + col0 + bc]);
            Bs[bk][bc + 0] = v.x;
            Bs[bk][bc + 1] = v.y;
            Bs[bk][bc + 2] = v.z;
            Bs[bk][bc + 3] = v.w;
        }
        __syncthreads();
        #pragma unroll
        for (int kk = 0; kk < BK; ++kk) {
            float a[4], b[4];
            #pragma unroll
            for (int i = 0; i < 4; ++i) a[i] = As[kk][tr * 4 + i];
            #pragma unroll
            for (int j = 0; j < 4; ++j) b[j] = Bs[kk][tc * 4 + j];
            #pragma unroll
            for (int i = 0; i < 4; ++i)
                #pragma unroll
                for (int j = 0; j < 4; ++j)
                    acc[i][j] += a[i] * b[j];
        }
        __syncthreads();
    }
    #pragma unroll
    for (int i = 0; i < 4; ++i) {
        int gr = row0 + tr * 4 + i;
        if (gr < M) {
            *reinterpret_cast<float4*>(&C[(size_t)gr * NHID + col0 + tc * 4]) =
                make_float4(acc[i][0], acc[i][1], acc[i][2], acc[i][3]);
        }
    }
}

// ---------------- spmm1: h[dst] += w * support1[src], F=256 ----------------
__global__ __launch_bounds__(256) void spmm1_kernel(const int* __restrict__ src,
                                                    const int* __restrict__ dst,
                                                    const float* __restrict__ w,
                                                    const float* __restrict__ sup,
                                                    float* __restrict__ h,
                                                    int E) {
    int e = blockIdx.x * 4 + (threadIdx.x >> 6);
    if (e >= E) return;
    int lane = threadIdx.x & 63;
    int s = src[e];
    int d = dst[e];
    float wt = w[e];
    float4 v = reinterpret_cast<const float4*>(sup + (size_t)s * NHID)[lane];
    float* hp = h + (size_t)d * NHID + lane * 4;
    atomicAdd(hp + 0, v.x * wt);
    atomicAdd(hp + 1, v.y * wt);
    atomicAdd(hp + 2, v.z * wt);
    atomicAdd(hp + 3, v.w * wt);
}

// ---------------- gemm2: c2 = relu(h + b1) @ W2  ([M,256]@[256,40]) ----------------
__global__ __launch_bounds__(256) void gemm2_kernel(const float* __restrict__ hbuf,
                                                    const float* __restrict__ b1,
                                                    const float* __restrict__ W2,
                                                    float* __restrict__ c2,
                                                    int M) {
    __shared__ float W2s[NHID * NCLASS];   // 40 KiB
    __shared__ float b1s[NHID];
    for (int i = threadIdx.x; i < NHID * NCLASS; i += 256) W2s[i] = W2[i];
    if (threadIdx.x < NHID) b1s[threadIdx.x] = b1[threadIdx.x];
    __syncthreads();

    int r = blockIdx.x * 256 + threadIdx.x;
    if (r >= M) return;
    float acc[NCLASS] = {};
    const float4* hp = reinterpret_cast<const float4*>(hbuf + (size_t)r * NHID);
    for (int k4 = 0; k4 < NHID / 4; ++k4) {
        float4 hv = hp[k4];
        float hvv[4] = {hv.x, hv.y, hv.z, hv.w};
        #pragma unroll
        for (int u = 0; u < 4; ++u) {
            int k = k4 * 4 + u;
            float hk = fmaxf(hvv[u] + b1s[k], 0.0f);
            #pragma unroll
            for (int j4 = 0; j4 < NCLASS / 4; ++j4) {
                float4 wv = *reinterpret_cast<const float4*>(&W2s[k * NCLASS + j4 * 4]);
                acc[j4 * 4 + 0] += hk * wv.x;
                acc[j4 * 4 + 1] += hk * wv.y;
                acc[j4 * 4 + 2] += hk * wv.z;
                acc[j4 * 4 + 3] += hk * wv.w;
            }
        }
    }
    float4* cp = reinterpret_cast<float4*>(c2 + (size_t)r * NCLASS);
    #pragma unroll
    for (int j4 = 0; j4 < NCLASS / 4; ++j4)
        cp[j4] = make_float4(acc[j4 * 4], acc[j4 * 4 + 1], acc[j4 * 4 + 2], acc[j4 * 4 + 3]);
}

// ---------------- spmm2: out[dst] += w * c2[src], F=40 ----------------
__global__ __launch_bounds__(256) void spmm2_kernel(const int* __restrict__ src,
                                                    const int* __restrict__ dst,
                                                    const float* __restrict__ w,
                                                    const float* __restrict__ c2,
                                                    float* __restrict__ out,
                                                    int E) {
    int gid = blockIdx.x * 256 + threadIdx.x;   // E*10 = 32M, fits int
    if (gid >= E * 10) return;
    int e = gid / 10;
    int c = gid - e * 10;
    int s = src[e];
    int d = dst[e];
    float wt = w[e];
    float4 v = reinterpret_cast<const float4*>(c2 + (size_t)s * NCLASS)[c];
    float* op = out + (size_t)d * NCLASS + c * 4;
    atomicAdd(op + 0, v.x * wt);
    atomicAdd(op + 1, v.y * wt);
    atomicAdd(op + 2, v.z * wt);
    atomicAdd(op + 3, v.w * wt);
}

// ---------------- softmax over 40 classes, thread per row ----------------
__global__ __launch_bounds__(256) void softmax_kernel(float* __restrict__ out, int M) {
    int r = blockIdx.x * 256 + threadIdx.x;
    if (r >= M) return;
    float4* pv = reinterpret_cast<float4*>(out + (size_t)r * NCLASS);
    float4 v[NCLASS / 4];
    float m = -1e30f;
    #pragma unroll
    for (int i = 0; i < NCLASS / 4; ++i) {
        v[i] = pv[i];
        m = fmaxf(m, fmaxf(fmaxf(v[i].x, v[i].y), fmaxf(v[i].z, v[i].w)));
    }
    float s = 0.f;
    #pragma unroll
    for (int i = 0; i < NCLASS / 4; ++i) {
        v[i].x = expf(v[i].x - m); s += v[i].x;
        v[i].y = expf(v[i].y - m); s += v[i].y;
        v[i].z = expf(v[i].z - m); s += v[i].z;
        v[i].w = expf(v[i].w - m); s += v[i].w;
    }
    float inv = 1.0f / s;
    #pragma unroll
    for (int i = 0; i < NCLASS / 4; ++i) {
        v[i].x *= inv; v[i].y *= inv; v[i].z *= inv; v[i].w *= inv;
        pv[i] = v[i];
    }
}

extern "C" void kernel_launch(void* const* d_in, const int* in_sizes, int n_in,
                              void* d_out, int out_size, void* d_ws, size_t ws_size,
                              hipStream_t stream) {
    const float* x  = (const float*)d_in[0];
    const int*   ei = (const int*)d_in[1];
    const float* ew = (const float*)d_in[2];
    const float* W1 = (const float*)d_in[3];
    const float* b1 = (const float*)d_in[4];
    const float* W2 = (const float*)d_in[5];
    float* out = (float*)d_out;

    const int M = in_sizes[0] / NFEAT;       // 100000
    const int E = in_sizes[1] / 2;           // 3200000
    const int* src = ei;
    const int* dst = ei + E;

    char* ws = (char*)d_ws;
    float* support1 = (float*)ws;                               // M*256 f32 = 102.4 MB
    float* hbuf     = (float*)(ws + (size_t)M * NHID * 4);      // M*256 f32 = 102.4 MB
    float* c2       = support1;                                 // reuse (support1 dead after spmm1)

    // 1) support1 = x @ W1
    dim3 g1((M + BM - 1) / BM, NHID / BN);
    gemm1_kernel<<<g1, 256, 0, stream>>>(x, W1, support1, M);

    // 2) h = A @ support1  (zero then atomic scatter)
    hipMemsetAsync(hbuf, 0, (size_t)M * NHID * 4, stream);
    spmm1_kernel<<<(E + 3) / 4, 256, 0, stream>>>(src, dst, ew, support1, hbuf, E);

    // 3) c2 = relu(h + b1) @ W2   (bias+relu fused into load)
    gemm2_kernel<<<(M + 255) / 256, 256, 0, stream>>>(hbuf, b1, W2, c2, M);

    // 4) out = A @ c2
    hipMemsetAsync(out, 0, (size_t)M * NCLASS * 4, stream);
    spmm2_kernel<<<((E * 10) + 255) / 256, 256, 0, stream>>>(src, dst, ew, c2, out, E);

    // 5) softmax rows
    softmax_kernel<<<(M + 255) / 256, 256, 0, stream>>>(out, M);
}

// Round 2
// 1747.302 us; speedup vs baseline: 7.5568x; 7.5568x over previous
//
#include <hip/hip_runtime.h>
#include <hip/hip_bf16.h>
#include <math.h>

// GCN forward: softmax( A * relu(A*(x@W1)+b1) @ W2 )
// N=100000 nodes, E=3.2M edges, F 512->256->40, all fp32.
// Strategy: device-built CSR (dst-sorted) -> gather-based SpMM, no atomics in
// the hot path. gemm2 fused into conv1 epilogue; softmax fused into conv2.

#define NFEAT 512
#define NHID  256
#define NCLASS 40

// ---------------- gemm1: support1 = x @ W1  ([M,512]@[512,256]) ----------------
#define BM 64
#define BN 64
#define BK 16

__global__ __launch_bounds__(256) void gemm1_kernel(const float* __restrict__ A,
                                                    const float* __restrict__ W,
                                                    float* __restrict__ C,
                                                    int M) {
    __shared__ float As[BK][BM + 1];
    __shared__ float Bs[BK][BN + 1];
    const int tid = threadIdx.x;
    const int row0 = blockIdx.x * BM;
    const int col0 = blockIdx.y * BN;
    const int tr = tid / 16;
    const int tc = tid % 16;
    float acc[4][4] = {};

    for (int k0 = 0; k0 < NFEAT; k0 += BK) {
        {
            int ar = tid >> 2;
            int ak = (tid & 3) << 2;
            int gr = row0 + ar;
            float4 v = make_float4(0.f, 0.f, 0.f, 0.f);
            if (gr < M) v = *reinterpret_cast<const float4*>(&A[(size_t)gr * NFEAT + k0 + ak]);
            As[ak + 0][ar] = v.x;
            As[ak + 1][ar] = v.y;
            As[ak + 2][ar] = v.z;
            As[ak + 3][ar] = v.w;
        }
        {
            int bk = tid >> 4;
            int bc = (tid & 15) << 2;
            float4 v = *reinterpret_cast<const float4*>(&W[(size_t)(k0 + bk) * NHID + col0 + bc]);
            Bs[bk][bc + 0] = v.x;
            Bs[bk][bc + 1] = v.y;
            Bs[bk][bc + 2] = v.z;
            Bs[bk][bc + 3] = v.w;
        }
        __syncthreads();
        #pragma unroll
        for (int kk = 0; kk < BK; ++kk) {
            float a[4], b[4];
            #pragma unroll
            for (int i = 0; i < 4; ++i) a[i] = As[kk][tr * 4 + i];
            #pragma unroll
            for (int j = 0; j < 4; ++j) b[j] = Bs[kk][tc * 4 + j];
            #pragma unroll
            for (int i = 0; i < 4; ++i)
                #pragma unroll
                for (int j = 0; j < 4; ++j)
                    acc[i][j] += a[i] * b[j];
        }
        __syncthreads();
    }
    #pragma unroll
    for (int i = 0; i < 4; ++i) {
        int gr = row0 + tr * 4 + i;
        if (gr < M) {
            *reinterpret_cast<float4*>(&C[(size_t)gr * NHID + col0 + tc * 4]) =
                make_float4(acc[i][0], acc[i][1], acc[i][2], acc[i][3]);
        }
    }
}

// ---------------- CSR build ----------------
__global__ __launch_bounds__(256) void hist_kernel(const int* __restrict__ dst,
                                                   int* __restrict__ deg, int E) {
    int e = blockIdx.x * 256 + threadIdx.x;
    if (e < E) atomicAdd(&deg[dst[e]], 1);
}

#define SCAN_CHUNK 1024
__global__ __launch_bounds__(256) void scan1_kernel(const int* __restrict__ deg,
                                                    int* __restrict__ part,
                                                    int* __restrict__ bsums, int N) {
    __shared__ int s[256];
    int b = blockIdx.x, t = threadIdx.x;
    int i0 = b * SCAN_CHUNK + t * 4;
    int d[4];
    #pragma unroll
    for (int u = 0; u < 4; ++u) d[u] = (i0 + u < N) ? deg[i0 + u] : 0;
    int loc = d[0] + d[1] + d[2] + d[3];
    s[t] = loc;
    __syncthreads();
    for (int off = 1; off < 256; off <<= 1) {
        int v = (t >= off) ? s[t - off] : 0;
        __syncthreads();
        s[t] += v;
        __syncthreads();
    }
    int run = s[t] - loc;          // exclusive base for this thread
    #pragma unroll
    for (int u = 0; u < 4; ++u) {
        if (i0 + u < N) part[i0 + u] = run;
        run += d[u];
    }
    if (t == 255) bsums[b] = s[255];
}

__global__ __launch_bounds__(128) void scan2_kernel(int* __restrict__ bsums, int nb) {
    __shared__ int s[128];
    int t = threadIdx.x;
    int v = (t < nb) ? bsums[t] : 0;
    s[t] = v;
    __syncthreads();
    for (int off = 1; off < 128; off <<= 1) {
        int x = (t >= off) ? s[t - off] : 0;
        __syncthreads();
        s[t] += x;
        __syncthreads();
    }
    if (t < nb) bsums[t] = s[t] - v;   // exclusive
}

__global__ __launch_bounds__(256) void scan3_kernel(int* __restrict__ row_start,
                                                    const int* __restrict__ bsums,
                                                    int N, int E) {
    int b = blockIdx.x, t = threadIdx.x;
    int i0 = b * SCAN_CHUNK + t * 4;
    int add = bsums[b];
    #pragma unroll
    for (int u = 0; u < 4; ++u)
        if (i0 + u < N) row_start[i0 + u] += add;
    if (b == 0 && t == 0) row_start[N] = E;
}

__global__ __launch_bounds__(256) void scatter_kernel(const int* __restrict__ src,
                                                      const int* __restrict__ dst,
                                                      const float* __restrict__ w,
                                                      int* __restrict__ cursor,
                                                      int2* __restrict__ csr, int E) {
    int e = blockIdx.x * 256 + threadIdx.x;
    if (e >= E) return;
    int d = dst[e];
    int pos = atomicAdd(&cursor[d], 1);
    csr[pos] = make_int2(src[e], __float_as_int(w[e]));
}

// ---------------- conv1: c2[n] = relu( (A @ support1)[n] + b1 ) @ W2 ----------------
// one block (256 threads) per dst node; thread t owns hidden feature t.
__global__ __launch_bounds__(256) void conv1_kernel(const int2* __restrict__ csr,
                                                    const int* __restrict__ row_start,
                                                    const float* __restrict__ sup,
                                                    const float* __restrict__ b1,
                                                    const float* __restrict__ W2,
                                                    float* __restrict__ c2, int N) {
    __shared__ float hrow[NHID];
    __shared__ float pbuf[160];
    int n = blockIdx.x;
    int t = threadIdx.x;
    int start = row_start[n], end = row_start[n + 1];
    float acc = 0.f;
    int j = start;
    for (; j + 1 < end; j += 2) {
        int2 e0 = csr[j];
        int2 e1 = csr[j + 1];
        float v0 = sup[(size_t)e0.x * NHID + t];
        float v1 = sup[(size_t)e1.x * NHID + t];
        acc += __int_as_float(e0.y) * v0;
        acc += __int_as_float(e1.y) * v1;
    }
    if (j < end) {
        int2 e0 = csr[j];
        acc += __int_as_float(e0.y) * sup[(size_t)e0.x * NHID + t];
    }
    hrow[t] = fmaxf(acc + b1[t], 0.f);
    __syncthreads();
    // c2 row = hrow @ W2  (256x40). threads 0..159: output j = t>>2, k-quarter q = t&3.
    if (t < 160) {
        int jc = t >> 2, q = t & 3;
        const float* hp = &hrow[q * 64];
        const float* wp = &W2[(size_t)(q * 64) * NCLASS + jc];
        float p = 0.f;
        #pragma unroll 8
        for (int k = 0; k < 64; ++k) p += hp[k] * wp[k * NCLASS];
        pbuf[t] = p;
    }
    __syncthreads();
    if (t < NCLASS) {
        c2[(size_t)n * NCLASS + t] =
            pbuf[t * 4] + pbuf[t * 4 + 1] + pbuf[t * 4 + 2] + pbuf[t * 4 + 3];
    }
}

// ---------------- conv2: out[n] = softmax( (A @ c2)[n] ) ----------------
// one wave (64 lanes) per dst node; lanes 0..39 own classes.
__global__ __launch_bounds__(256) void conv2_kernel(const int2* __restrict__ csr,
                                                    const int* __restrict__ row_start,
                                                    const float* __restrict__ c2,
                                                    float* __restrict__ out, int N) {
    int wave = threadIdx.x >> 6;
    int lane = threadIdx.x & 63;
    int n = blockIdx.x * 4 + wave;
    if (n >= N) return;
    int start = row_start[n], end = row_start[n + 1];
    float acc = 0.f;
    int j = start;
    for (; j + 1 < end; j += 2) {
        int2 e0 = csr[j];
        int2 e1 = csr[j + 1];
        if (lane < NCLASS) {
            acc += __int_as_float(e0.y) * c2[(size_t)e0.x * NCLASS + lane];
            acc += __int_as_float(e1.y) * c2[(size_t)e1.x * NCLASS + lane];
        }
    }
    if (j < end) {
        int2 e0 = csr[j];
        if (lane < NCLASS) acc += __int_as_float(e0.y) * c2[(size_t)e0.x * NCLASS + lane];
    }
    // softmax across lanes 0..39 (all 64 lanes join the butterflies)
    float m = (lane < NCLASS) ? acc : -INFINITY;
    #pragma unroll
    for (int off = 32; off > 0; off >>= 1) m = fmaxf(m, __shfl_xor(m, off, 64));
    float e = (lane < NCLASS) ? expf(acc - m) : 0.f;
    float s = e;
    #pragma unroll
    for (int off = 32; off > 0; off >>= 1) s += __shfl_xor(s, off, 64);
    if (lane < NCLASS) out[(size_t)n * NCLASS + lane] = e / s;
}

extern "C" void kernel_launch(void* const* d_in, const int* in_sizes, int n_in,
                              void* d_out, int out_size, void* d_ws, size_t ws_size,
                              hipStream_t stream) {
    const float* x  = (const float*)d_in[0];
    const int*   ei = (const int*)d_in[1];
    const float* ew = (const float*)d_in[2];
    const float* W1 = (const float*)d_in[3];
    const float* b1 = (const float*)d_in[4];
    const float* W2 = (const float*)d_in[5];
    float* out = (float*)d_out;

    const int M = in_sizes[0] / NFEAT;       // 100000
    const int E = in_sizes[1] / 2;           // 3200000
    const int* src = ei;
    const int* dst = ei + E;

    // workspace layout (~145 MB)
    float* support1 = (float*)d_ws;                       // M*256 f32 = 102.4 MB
    float* c2       = support1 + (size_t)M * NHID;        // M*40  f32 = 16 MB
    int2*  csr      = (int2*)(c2 + (size_t)M * NCLASS);   // E int2    = 25.6 MB
    int*   deg      = (int*)(csr + E);                    // M
    int*   row_start= deg + M;                            // M+1
    int*   cursor   = row_start + (M + 1);                // M
    int*   bsums    = cursor + M;                         // 128

    const int nscan = (M + SCAN_CHUNK - 1) / SCAN_CHUNK;  // 98

    // ---- CSR build ----
    hipMemsetAsync(deg, 0, (size_t)M * 4, stream);
    hist_kernel<<<(E + 255) / 256, 256, 0, stream>>>(dst, deg, E);
    scan1_kernel<<<nscan, 256, 0, stream>>>(deg, row_start, bsums, M);
    scan2_kernel<<<1, 128, 0, stream>>>(bsums, nscan);
    scan3_kernel<<<nscan, 256, 0, stream>>>(row_start, bsums, M, E);
    hipMemcpyAsync(cursor, row_start, (size_t)M * 4, hipMemcpyDeviceToDevice, stream);
    scatter_kernel<<<(E + 255) / 256, 256, 0, stream>>>(src, dst, ew, cursor, csr, E);

    // ---- dense + sparse pipeline ----
    dim3 g1((M + BM - 1) / BM, NHID / BN);
    gemm1_kernel<<<g1, 256, 0, stream>>>(x, W1, support1, M);

    conv1_kernel<<<M, 256, 0, stream>>>(csr, row_start, support1, b1, W2, c2, M);
    conv2_kernel<<<(M + 3) / 4, 256, 0, stream>>>(csr, row_start, c2, out, M);
}

// Round 3
// 1698.362 us; speedup vs baseline: 7.7746x; 1.0288x over previous
//
#include <hip/hip_runtime.h>
#include <hip/hip_bf16.h>
#include <math.h>

// GCN forward: softmax( A * relu(A*(x@W1)+b1) @ W2 )
// N=100000 nodes, E=3.2M edges, F 512->256->40, all fp32.
// CSR (dst-sorted) built on device -> gather SpMM, no atomics in hot path.
// gemm2 fused into conv1 epilogue (via pre-transposed W2T, coalesced streams);
// softmax fused into conv2.

#define NFEAT 512
#define NHID  256
#define NCLASS 40

// ---------------- gemm1: support1 = x @ W1  ([M,512]@[512,256]) ----------------
// 128x128 tile, BK=8, 256 threads, 8x8 accumulators per thread (flop:LDS-byte = 2:1)
#define G1_BM 128
#define G1_BN 128
#define G1_BK 8

__global__ __launch_bounds__(256) void gemm1_kernel(const float* __restrict__ A,
                                                    const float* __restrict__ W,
                                                    float* __restrict__ C,
                                                    int M) {
    __shared__ float As[G1_BK][G1_BM + 4];
    __shared__ float Bs[G1_BK][G1_BN + 4];
    const int tid = threadIdx.x;
    const int row0 = blockIdx.x * G1_BM;
    const int col0 = blockIdx.y * G1_BN;     // 0 or 128
    const int tr = tid >> 4;                 // 0..15
    const int tc = tid & 15;                 // 0..15
    float acc[8][8] = {};

    const int ar = tid >> 1;                 // 0..127
    const int ak = (tid & 1) << 2;           // 0 or 4
    const int bk = tid >> 5;                 // 0..7
    const int bc = (tid & 31) << 2;          // 0..124

    for (int k0 = 0; k0 < NFEAT; k0 += G1_BK) {
        {
            int gr = row0 + ar;
            float4 av = make_float4(0.f, 0.f, 0.f, 0.f);
            if (gr < M) av = *reinterpret_cast<const float4*>(&A[(size_t)gr * NFEAT + k0 + ak]);
            As[ak + 0][ar] = av.x;
            As[ak + 1][ar] = av.y;
            As[ak + 2][ar] = av.z;
            As[ak + 3][ar] = av.w;
        }
        {
            float4 bv = *reinterpret_cast<const float4*>(&W[(size_t)(k0 + bk) * NHID + col0 + bc]);
            Bs[bk][bc + 0] = bv.x;
            Bs[bk][bc + 1] = bv.y;
            Bs[bk][bc + 2] = bv.z;
            Bs[bk][bc + 3] = bv.w;
        }
        __syncthreads();
        #pragma unroll
        for (int kk = 0; kk < G1_BK; ++kk) {
            float a[8], b[8];
            #pragma unroll
            for (int i = 0; i < 8; ++i) a[i] = As[kk][tr * 8 + i];
            #pragma unroll
            for (int j = 0; j < 8; ++j) b[j] = Bs[kk][tc * 8 + j];
            #pragma unroll
            for (int i = 0; i < 8; ++i)
                #pragma unroll
                for (int j = 0; j < 8; ++j)
                    acc[i][j] += a[i] * b[j];
        }
        __syncthreads();
    }
    #pragma unroll
    for (int i = 0; i < 8; ++i) {
        int gr = row0 + tr * 8 + i;
        if (gr < M) {
            float* cp = &C[(size_t)gr * NHID + col0 + tc * 8];
            *reinterpret_cast<float4*>(cp) =
                make_float4(acc[i][0], acc[i][1], acc[i][2], acc[i][3]);
            *reinterpret_cast<float4*>(cp + 4) =
                make_float4(acc[i][4], acc[i][5], acc[i][6], acc[i][7]);
        }
    }
}

// ---------------- W2 transpose: W2T[40][256] <- W2[256][40] ----------------
__global__ __launch_bounds__(256) void transpose_w2_kernel(const float* __restrict__ W2,
                                                           float* __restrict__ W2T) {
    for (int i = threadIdx.x; i < NHID * NCLASS; i += 256) {
        int k = i / NCLASS, j = i - k * NCLASS;
        W2T[(size_t)j * NHID + k] = W2[i];
    }
}

// ---------------- CSR build ----------------
__global__ __launch_bounds__(256) void hist_kernel(const int* __restrict__ dst,
                                                   int* __restrict__ deg, int E) {
    int e = blockIdx.x * 256 + threadIdx.x;
    if (e < E) atomicAdd(&deg[dst[e]], 1);
}

#define SCAN_CHUNK 1024
__global__ __launch_bounds__(256) void scan1_kernel(const int* __restrict__ deg,
                                                    int* __restrict__ part,
                                                    int* __restrict__ bsums, int N) {
    __shared__ int s[256];
    int b = blockIdx.x, t = threadIdx.x;
    int i0 = b * SCAN_CHUNK + t * 4;
    int d[4];
    #pragma unroll
    for (int u = 0; u < 4; ++u) d[u] = (i0 + u < N) ? deg[i0 + u] : 0;
    int loc = d[0] + d[1] + d[2] + d[3];
    s[t] = loc;
    __syncthreads();
    for (int off = 1; off < 256; off <<= 1) {
        int v = (t >= off) ? s[t - off] : 0;
        __syncthreads();
        s[t] += v;
        __syncthreads();
    }
    int run = s[t] - loc;
    #pragma unroll
    for (int u = 0; u < 4; ++u) {
        if (i0 + u < N) part[i0 + u] = run;
        run += d[u];
    }
    if (t == 255) bsums[b] = s[255];
}

__global__ __launch_bounds__(128) void scan2_kernel(int* __restrict__ bsums, int nb) {
    __shared__ int s[128];
    int t = threadIdx.x;
    int v = (t < nb) ? bsums[t] : 0;
    s[t] = v;
    __syncthreads();
    for (int off = 1; off < 128; off <<= 1) {
        int x = (t >= off) ? s[t - off] : 0;
        __syncthreads();
        s[t] += x;
        __syncthreads();
    }
    if (t < nb) bsums[t] = s[t] - v;
}

__global__ __launch_bounds__(256) void scan3_kernel(int* __restrict__ row_start,
                                                    const int* __restrict__ bsums,
                                                    int N, int E) {
    int b = blockIdx.x, t = threadIdx.x;
    int i0 = b * SCAN_CHUNK + t * 4;
    int add = bsums[b];
    #pragma unroll
    for (int u = 0; u < 4; ++u)
        if (i0 + u < N) row_start[i0 + u] += add;
    if (b == 0 && t == 0) row_start[N] = E;
}

__global__ __launch_bounds__(256) void scatter_kernel(const int* __restrict__ src,
                                                      const int* __restrict__ dst,
                                                      const float* __restrict__ w,
                                                      int* __restrict__ cursor,
                                                      int2* __restrict__ csr, int E) {
    int e = blockIdx.x * 256 + threadIdx.x;
    if (e >= E) return;
    int d = dst[e];
    int pos = atomicAdd(&cursor[d], 1);
    csr[pos] = make_int2(src[e], __float_as_int(w[e]));
}

// ---------------- conv1: c2[n] = relu( (A @ support1)[n] + b1 ) @ W2 ----------------
// one block (256 threads) per dst node; thread t owns hidden feature t.
// Epilogue uses W2T (transposed): thread (jc,q) streams 64 consecutive floats.
__global__ __launch_bounds__(256) void conv1_kernel(const int2* __restrict__ csr,
                                                    const int* __restrict__ row_start,
                                                    const float* __restrict__ sup,
                                                    const float* __restrict__ b1,
                                                    const float* __restrict__ w2t,
                                                    float* __restrict__ c2, int N) {
    __shared__ float hrow[NHID];
    __shared__ float pbuf[160];
    int n = blockIdx.x;
    int t = threadIdx.x;
    int start = row_start[n], end = row_start[n + 1];
    float acc = 0.f;
    int j = start;
    for (; j + 3 < end; j += 4) {
        int2 e0 = csr[j];
        int2 e1 = csr[j + 1];
        int2 e2 = csr[j + 2];
        int2 e3 = csr[j + 3];
        float v0 = sup[(size_t)e0.x * NHID + t];
        float v1 = sup[(size_t)e1.x * NHID + t];
        float v2 = sup[(size_t)e2.x * NHID + t];
        float v3 = sup[(size_t)e3.x * NHID + t];
        acc += __int_as_float(e0.y) * v0 + __int_as_float(e1.y) * v1
             + __int_as_float(e2.y) * v2 + __int_as_float(e3.y) * v3;
    }
    for (; j < end; ++j) {
        int2 e0 = csr[j];
        acc += __int_as_float(e0.y) * sup[(size_t)e0.x * NHID + t];
    }
    hrow[t] = fmaxf(acc + b1[t], 0.f);
    __syncthreads();
    // c2 row = hrow @ W2. threads t<160: jc = t%40, quarter q = t/40.
    if (t < 160) {
        int jc = t % 40, q = t / 40;
        const float4* hp = reinterpret_cast<const float4*>(&hrow[q * 64]);
        const float4* wp = reinterpret_cast<const float4*>(&w2t[(size_t)jc * NHID + q * 64]);
        float p = 0.f;
        #pragma unroll
        for (int kk = 0; kk < 16; ++kk) {
            float4 h4 = hp[kk];
            float4 w4 = wp[kk];
            p += h4.x * w4.x + h4.y * w4.y + h4.z * w4.z + h4.w * w4.w;
        }
        pbuf[t] = p;
    }
    __syncthreads();
    if (t < NCLASS) {
        c2[(size_t)n * NCLASS + t] = pbuf[t] + pbuf[t + 40] + pbuf[t + 80] + pbuf[t + 120];
    }
}

// ---------------- conv2: out[n] = softmax( (A @ c2)[n] ) ----------------
// one wave (64 lanes) per dst node; lanes 0..39 own classes.
__global__ __launch_bounds__(256) void conv2_kernel(const int2* __restrict__ csr,
                                                    const int* __restrict__ row_start,
                                                    const float* __restrict__ c2,
                                                    float* __restrict__ out, int N) {
    int wave = threadIdx.x >> 6;
    int lane = threadIdx.x & 63;
    int n = blockIdx.x * 4 + wave;
    if (n >= N) return;
    int start = row_start[n], end = row_start[n + 1];
    float acc = 0.f;
    int j = start;
    for (; j + 3 < end; j += 4) {
        int2 e0 = csr[j];
        int2 e1 = csr[j + 1];
        int2 e2 = csr[j + 2];
        int2 e3 = csr[j + 3];
        if (lane < NCLASS) {
            acc += __int_as_float(e0.y) * c2[(size_t)e0.x * NCLASS + lane]
                 + __int_as_float(e1.y) * c2[(size_t)e1.x * NCLASS + lane]
                 + __int_as_float(e2.y) * c2[(size_t)e2.x * NCLASS + lane]
                 + __int_as_float(e3.y) * c2[(size_t)e3.x * NCLASS + lane];
        }
    }
    for (; j < end; ++j) {
        int2 e0 = csr[j];
        if (lane < NCLASS) acc += __int_as_float(e0.y) * c2[(size_t)e0.x * NCLASS + lane];
    }
    float m = (lane < NCLASS) ? acc : -INFINITY;
    #pragma unroll
    for (int off = 32; off > 0; off >>= 1) m = fmaxf(m, __shfl_xor(m, off, 64));
    float e = (lane < NCLASS) ? expf(acc - m) : 0.f;
    float s = e;
    #pragma unroll
    for (int off = 32; off > 0; off >>= 1) s += __shfl_xor(s, off, 64);
    if (lane < NCLASS) out[(size_t)n * NCLASS + lane] = e / s;
}

extern "C" void kernel_launch(void* const* d_in, const int* in_sizes, int n_in,
                              void* d_out, int out_size, void* d_ws, size_t ws_size,
                              hipStream_t stream) {
    const float* x  = (const float*)d_in[0];
    const int*   ei = (const int*)d_in[1];
    const float* ew = (const float*)d_in[2];
    const float* W1 = (const float*)d_in[3];
    const float* b1 = (const float*)d_in[4];
    const float* W2 = (const float*)d_in[5];
    float* out = (float*)d_out;

    const int M = in_sizes[0] / NFEAT;       // 100000
    const int E = in_sizes[1] / 2;           // 3200000
    const int* src = ei;
    const int* dst = ei + E;

    // workspace layout (~145.4 MB)
    float* support1 = (float*)d_ws;                       // M*256 f32 = 102.4 MB
    float* c2       = support1 + (size_t)M * NHID;        // M*40  f32 = 16 MB
    int2*  csr      = (int2*)(c2 + (size_t)M * NCLASS);   // E int2    = 25.6 MB
    int*   deg      = (int*)(csr + E);                    // M
    int*   row_start= deg + M;                            // M+1
    int*   cursor   = row_start + (M + 1);                // M
    int*   bsums    = cursor + M;                         // 128
    float* w2t      = (float*)(bsums + 128);              // 40*256 f32 = 40 KB

    const int nscan = (M + SCAN_CHUNK - 1) / SCAN_CHUNK;  // 98

    // ---- CSR build ----
    hipMemsetAsync(deg, 0, (size_t)M * 4, stream);
    hist_kernel<<<(E + 255) / 256, 256, 0, stream>>>(dst, deg, E);
    scan1_kernel<<<nscan, 256, 0, stream>>>(deg, row_start, bsums, M);
    scan2_kernel<<<1, 128, 0, stream>>>(bsums, nscan);
    scan3_kernel<<<nscan, 256, 0, stream>>>(row_start, bsums, M, E);
    hipMemcpyAsync(cursor, row_start, (size_t)M * 4, hipMemcpyDeviceToDevice, stream);
    scatter_kernel<<<(E + 255) / 256, 256, 0, stream>>>(src, dst, ew, cursor, csr, E);
    transpose_w2_kernel<<<1, 256, 0, stream>>>(W2, w2t);

    // ---- dense + sparse pipeline ----
    dim3 g1((M + G1_BM - 1) / G1_BM, NHID / G1_BN);
    gemm1_kernel<<<g1, 256, 0, stream>>>(x, W1, support1, M);

    conv1_kernel<<<M, 256, 0, stream>>>(csr, row_start, support1, b1, w2t, c2, M);
    conv2_kernel<<<(M + 3) / 4, 256, 0, stream>>>(csr, row_start, c2, out, M);
}

// Round 4
// 1544.642 us; speedup vs baseline: 8.5483x; 1.0995x over previous
//
#include <hip/hip_runtime.h>
#include <hip/hip_bf16.h>
#include <math.h>

// GCN forward: softmax( A * relu(A*(x@W1)+b1) @ W2 )
// N=100000 nodes, E=3.2M edges, F 512->256->40, all fp32.
// CSR (dst-sorted) built on device -> gather SpMM, no atomics in hot path.
// conv1: edge-staged-in-LDS, wave-per-edge-subset, float4 lanes (latency fix).
// gemm2 fused into conv1 epilogue; softmax fused into conv2.

#define NFEAT 512
#define NHID  256
#define NCLASS 40

// ---------------- gemm1: support1 = x @ W1  ([M,512]@[512,256]) ----------------
#define G1_BM 128
#define G1_BN 128
#define G1_BK 8

__global__ __launch_bounds__(256) void gemm1_kernel(const float* __restrict__ A,
                                                    const float* __restrict__ W,
                                                    float* __restrict__ C,
                                                    int M) {
    __shared__ float As[G1_BK][G1_BM + 4];
    __shared__ float Bs[G1_BK][G1_BN + 4];
    const int tid = threadIdx.x;
    const int row0 = blockIdx.x * G1_BM;
    const int col0 = blockIdx.y * G1_BN;
    const int tr = tid >> 4;
    const int tc = tid & 15;
    float acc[8][8] = {};

    const int ar = tid >> 1;
    const int ak = (tid & 1) << 2;
    const int bk = tid >> 5;
    const int bc = (tid & 31) << 2;

    for (int k0 = 0; k0 < NFEAT; k0 += G1_BK) {
        {
            int gr = row0 + ar;
            float4 av = make_float4(0.f, 0.f, 0.f, 0.f);
            if (gr < M) av = *reinterpret_cast<const float4*>(&A[(size_t)gr * NFEAT + k0 + ak]);
            As[ak + 0][ar] = av.x;
            As[ak + 1][ar] = av.y;
            As[ak + 2][ar] = av.z;
            As[ak + 3][ar] = av.w;
        }
        {
            float4 bv = *reinterpret_cast<const float4*>(&W[(size_t)(k0 + bk) * NHID + col0 + bc]);
            Bs[bk][bc + 0] = bv.x;
            Bs[bk][bc + 1] = bv.y;
            Bs[bk][bc + 2] = bv.z;
            Bs[bk][bc + 3] = bv.w;
        }
        __syncthreads();
        #pragma unroll
        for (int kk = 0; kk < G1_BK; ++kk) {
            float a[8], b[8];
            #pragma unroll
            for (int i = 0; i < 8; ++i) a[i] = As[kk][tr * 8 + i];
            #pragma unroll
            for (int j = 0; j < 8; ++j) b[j] = Bs[kk][tc * 8 + j];
            #pragma unroll
            for (int i = 0; i < 8; ++i)
                #pragma unroll
                for (int j = 0; j < 8; ++j)
                    acc[i][j] += a[i] * b[j];
        }
        __syncthreads();
    }
    #pragma unroll
    for (int i = 0; i < 8; ++i) {
        int gr = row0 + tr * 8 + i;
        if (gr < M) {
            float* cp = &C[(size_t)gr * NHID + col0 + tc * 8];
            *reinterpret_cast<float4*>(cp) =
                make_float4(acc[i][0], acc[i][1], acc[i][2], acc[i][3]);
            *reinterpret_cast<float4*>(cp + 4) =
                make_float4(acc[i][4], acc[i][5], acc[i][6], acc[i][7]);
        }
    }
}

// ---------------- W2 transpose: W2T[40][256] <- W2[256][40] ----------------
__global__ __launch_bounds__(256) void transpose_w2_kernel(const float* __restrict__ W2,
                                                           float* __restrict__ W2T) {
    for (int i = threadIdx.x; i < NHID * NCLASS; i += 256) {
        int k = i / NCLASS, j = i - k * NCLASS;
        W2T[(size_t)j * NHID + k] = W2[i];
    }
}

// ---------------- CSR build ----------------
__global__ __launch_bounds__(256) void hist_kernel(const int* __restrict__ dst,
                                                   int* __restrict__ deg, int E) {
    int e = blockIdx.x * 256 + threadIdx.x;
    if (e < E) atomicAdd(&deg[dst[e]], 1);
}

#define SCAN_CHUNK 1024
__global__ __launch_bounds__(256) void scan1_kernel(const int* __restrict__ deg,
                                                    int* __restrict__ part,
                                                    int* __restrict__ bsums, int N) {
    __shared__ int s[256];
    int b = blockIdx.x, t = threadIdx.x;
    int i0 = b * SCAN_CHUNK + t * 4;
    int d[4];
    #pragma unroll
    for (int u = 0; u < 4; ++u) d[u] = (i0 + u < N) ? deg[i0 + u] : 0;
    int loc = d[0] + d[1] + d[2] + d[3];
    s[t] = loc;
    __syncthreads();
    for (int off = 1; off < 256; off <<= 1) {
        int v = (t >= off) ? s[t - off] : 0;
        __syncthreads();
        s[t] += v;
        __syncthreads();
    }
    int run = s[t] - loc;
    #pragma unroll
    for (int u = 0; u < 4; ++u) {
        if (i0 + u < N) part[i0 + u] = run;
        run += d[u];
    }
    if (t == 255) bsums[b] = s[255];
}

__global__ __launch_bounds__(128) void scan2_kernel(int* __restrict__ bsums, int nb) {
    __shared__ int s[128];
    int t = threadIdx.x;
    int v = (t < nb) ? bsums[t] : 0;
    s[t] = v;
    __syncthreads();
    for (int off = 1; off < 128; off <<= 1) {
        int x = (t >= off) ? s[t - off] : 0;
        __syncthreads();
        s[t] += x;
        __syncthreads();
    }
    if (t < nb) bsums[t] = s[t] - v;
}

__global__ __launch_bounds__(256) void scan3_kernel(int* __restrict__ row_start,
                                                    const int* __restrict__ bsums,
                                                    int N, int E) {
    int b = blockIdx.x, t = threadIdx.x;
    int i0 = b * SCAN_CHUNK + t * 4;
    int add = bsums[b];
    #pragma unroll
    for (int u = 0; u < 4; ++u)
        if (i0 + u < N) row_start[i0 + u] += add;
    if (b == 0 && t == 0) row_start[N] = E;
}

__global__ __launch_bounds__(256) void scatter_kernel(const int* __restrict__ src,
                                                      const int* __restrict__ dst,
                                                      const float* __restrict__ w,
                                                      int* __restrict__ cursor,
                                                      int2* __restrict__ csr, int E) {
    int e = blockIdx.x * 256 + threadIdx.x;
    if (e >= E) return;
    int d = dst[e];
    int pos = atomicAdd(&cursor[d], 1);
    csr[pos] = make_int2(src[e], __float_as_int(w[e]));
}

// ---------------- conv1: c2[n] = relu( (A @ support1)[n] + b1 ) @ W2 ----------------
// One block per dst node. Edges staged in LDS; wave w takes edges == w (mod 4);
// lane l loads float4 features [4l..4l+3]; 4 edges in flight per iteration.
#define C1_CHUNK 256
__global__ __launch_bounds__(256) void conv1_kernel(const int2* __restrict__ csr,
                                                    const int* __restrict__ row_start,
                                                    const float* __restrict__ sup,
                                                    const float* __restrict__ b1,
                                                    const float* __restrict__ w2t,
                                                    float* __restrict__ c2, int N) {
    __shared__ int2  eb[C1_CHUNK];
    __shared__ float pacc[4][NHID];
    __shared__ float hrow[NHID];
    __shared__ float pbuf[160];
    const int n = blockIdx.x;
    const int t = threadIdx.x;
    const int wave = t >> 6;
    const int lane = t & 63;
    const int start = row_start[n], end = row_start[n + 1];

    float4 acc = make_float4(0.f, 0.f, 0.f, 0.f);
    for (int c0 = start; c0 < end; c0 += C1_CHUNK) {
        int clen = min(C1_CHUNK, end - c0);
        __syncthreads();
        if (t < clen) eb[t] = csr[c0 + t];
        __syncthreads();
        int j = wave;
        for (; j + 12 < clen; j += 16) {
            int2 e0 = eb[j];
            int2 e1 = eb[j + 4];
            int2 e2 = eb[j + 8];
            int2 e3 = eb[j + 12];
            float4 v0 = reinterpret_cast<const float4*>(sup + (size_t)e0.x * NHID)[lane];
            float4 v1 = reinterpret_cast<const float4*>(sup + (size_t)e1.x * NHID)[lane];
            float4 v2 = reinterpret_cast<const float4*>(sup + (size_t)e2.x * NHID)[lane];
            float4 v3 = reinterpret_cast<const float4*>(sup + (size_t)e3.x * NHID)[lane];
            float w0 = __int_as_float(e0.y), w1 = __int_as_float(e1.y);
            float w2 = __int_as_float(e2.y), w3 = __int_as_float(e3.y);
            acc.x += w0 * v0.x + w1 * v1.x + w2 * v2.x + w3 * v3.x;
            acc.y += w0 * v0.y + w1 * v1.y + w2 * v2.y + w3 * v3.y;
            acc.z += w0 * v0.z + w1 * v1.z + w2 * v2.z + w3 * v3.z;
            acc.w += w0 * v0.w + w1 * v1.w + w2 * v2.w + w3 * v3.w;
        }
        for (; j < clen; j += 4) {
            int2 e0 = eb[j];
            float w0 = __int_as_float(e0.y);
            float4 v0 = reinterpret_cast<const float4*>(sup + (size_t)e0.x * NHID)[lane];
            acc.x += w0 * v0.x;
            acc.y += w0 * v0.y;
            acc.z += w0 * v0.z;
            acc.w += w0 * v0.w;
        }
    }
    *reinterpret_cast<float4*>(&pacc[wave][lane * 4]) = acc;
    __syncthreads();
    hrow[t] = fmaxf(pacc[0][t] + pacc[1][t] + pacc[2][t] + pacc[3][t] + b1[t], 0.f);
    __syncthreads();
    // c2 row = hrow @ W2 via W2T: thread (jc = t%40, q = t/40) streams 64 floats.
    if (t < 160) {
        int jc = t % 40, q = t / 40;
        const float4* hp = reinterpret_cast<const float4*>(&hrow[q * 64]);
        const float4* wp = reinterpret_cast<const float4*>(&w2t[(size_t)jc * NHID + q * 64]);
        float p = 0.f;
        #pragma unroll
        for (int kk = 0; kk < 16; ++kk) {
            float4 h4 = hp[kk];
            float4 w4 = wp[kk];
            p += h4.x * w4.x + h4.y * w4.y + h4.z * w4.z + h4.w * w4.w;
        }
        pbuf[t] = p;
    }
    __syncthreads();
    if (t < NCLASS) {
        c2[(size_t)n * NCLASS + t] = pbuf[t] + pbuf[t + 40] + pbuf[t + 80] + pbuf[t + 120];
    }
}

// ---------------- conv2: out[n] = softmax( (A @ c2)[n] ) ----------------
// one wave per dst node; lanes 0..39 own classes; 8 edges in flight.
__global__ __launch_bounds__(256) void conv2_kernel(const int2* __restrict__ csr,
                                                    const int* __restrict__ row_start,
                                                    const float* __restrict__ c2,
                                                    float* __restrict__ out, int N) {
    int wave = threadIdx.x >> 6;
    int lane = threadIdx.x & 63;
    int n = blockIdx.x * 4 + wave;
    if (n >= N) return;
    int start = row_start[n], end = row_start[n + 1];
    bool act = lane < NCLASS;
    float acc = 0.f;
    int j = start;
    for (; j + 7 < end; j += 8) {
        int2 e0 = csr[j];
        int2 e1 = csr[j + 1];
        int2 e2 = csr[j + 2];
        int2 e3 = csr[j + 3];
        int2 e4 = csr[j + 4];
        int2 e5 = csr[j + 5];
        int2 e6 = csr[j + 6];
        int2 e7 = csr[j + 7];
        if (act) {
            float s0 = c2[(size_t)e0.x * NCLASS + lane];
            float s1 = c2[(size_t)e1.x * NCLASS + lane];
            float s2 = c2[(size_t)e2.x * NCLASS + lane];
            float s3 = c2[(size_t)e3.x * NCLASS + lane];
            float s4 = c2[(size_t)e4.x * NCLASS + lane];
            float s5 = c2[(size_t)e5.x * NCLASS + lane];
            float s6 = c2[(size_t)e6.x * NCLASS + lane];
            float s7 = c2[(size_t)e7.x * NCLASS + lane];
            acc += __int_as_float(e0.y) * s0 + __int_as_float(e1.y) * s1
                 + __int_as_float(e2.y) * s2 + __int_as_float(e3.y) * s3
                 + __int_as_float(e4.y) * s4 + __int_as_float(e5.y) * s5
                 + __int_as_float(e6.y) * s6 + __int_as_float(e7.y) * s7;
        }
    }
    for (; j < end; ++j) {
        int2 e0 = csr[j];
        if (act) acc += __int_as_float(e0.y) * c2[(size_t)e0.x * NCLASS + lane];
    }
    float m = act ? acc : -INFINITY;
    #pragma unroll
    for (int off = 32; off > 0; off >>= 1) m = fmaxf(m, __shfl_xor(m, off, 64));
    float e = act ? expf(acc - m) : 0.f;
    float s = e;
    #pragma unroll
    for (int off = 32; off > 0; off >>= 1) s += __shfl_xor(s, off, 64);
    if (act) out[(size_t)n * NCLASS + lane] = e / s;
}

extern "C" void kernel_launch(void* const* d_in, const int* in_sizes, int n_in,
                              void* d_out, int out_size, void* d_ws, size_t ws_size,
                              hipStream_t stream) {
    const float* x  = (const float*)d_in[0];
    const int*   ei = (const int*)d_in[1];
    const float* ew = (const float*)d_in[2];
    const float* W1 = (const float*)d_in[3];
    const float* b1 = (const float*)d_in[4];
    const float* W2 = (const float*)d_in[5];
    float* out = (float*)d_out;

    const int M = in_sizes[0] / NFEAT;       // 100000
    const int E = in_sizes[1] / 2;           // 3200000
    const int* src = ei;
    const int* dst = ei + E;

    // workspace layout (~145.4 MB)
    float* support1 = (float*)d_ws;                       // M*256 f32 = 102.4 MB
    float* c2       = support1 + (size_t)M * NHID;        // M*40  f32 = 16 MB
    int2*  csr      = (int2*)(c2 + (size_t)M * NCLASS);   // E int2    = 25.6 MB
    int*   deg      = (int*)(csr + E);                    // M
    int*   row_start= deg + M;                            // M+1
    int*   cursor   = row_start + (M + 1);                // M
    int*   bsums    = cursor + M;                         // 128
    float* w2t      = (float*)(bsums + 128);              // 40*256 f32 = 40 KB

    const int nscan = (M + SCAN_CHUNK - 1) / SCAN_CHUNK;  // 98

    // ---- CSR build ----
    hipMemsetAsync(deg, 0, (size_t)M * 4, stream);
    hist_kernel<<<(E + 255) / 256, 256, 0, stream>>>(dst, deg, E);
    scan1_kernel<<<nscan, 256, 0, stream>>>(deg, row_start, bsums, M);
    scan2_kernel<<<1, 128, 0, stream>>>(bsums, nscan);
    scan3_kernel<<<nscan, 256, 0, stream>>>(row_start, bsums, M, E);
    hipMemcpyAsync(cursor, row_start, (size_t)M * 4, hipMemcpyDeviceToDevice, stream);
    scatter_kernel<<<(E + 255) / 256, 256, 0, stream>>>(src, dst, ew, cursor, csr, E);
    transpose_w2_kernel<<<1, 256, 0, stream>>>(W2, w2t);

    // ---- dense + sparse pipeline ----
    dim3 g1((M + G1_BM - 1) / G1_BM, NHID / G1_BN);
    gemm1_kernel<<<g1, 256, 0, stream>>>(x, W1, support1, M);

    conv1_kernel<<<M, 256, 0, stream>>>(csr, row_start, support1, b1, w2t, c2, M);
    conv2_kernel<<<(M + 3) / 4, 256, 0, stream>>>(csr, row_start, c2, out, M);
}

// Round 6
// 1212.464 us; speedup vs baseline: 10.8903x; 1.2740x over previous
//
#include <hip/hip_runtime.h>
#include <hip/hip_bf16.h>
#include <math.h>

// GCN forward: softmax( A * relu(A*(x@W1)+b1) @ W2 )
// N=100000 nodes, E=3.2M edges, F 512->256->40.
// CSR (dst-sorted) built on device -> gather SpMM, no atomics in hot path.
// support1 kept in FP16 (51 MB, L3-resident) -> conv1 gathers half the bytes.
// fp16 (not bf16): 10 mantissa bits keeps absmax ~8x lower (round-5 lesson).
// gemm1 done with fp16 MFMA. gemm2 fused into conv1 epilogue; softmax into conv2.

#define NFEAT 512
#define NHID  256
#define NCLASS 40

typedef _Float16 f16x8 __attribute__((ext_vector_type(8)));
typedef float    f32x4 __attribute__((ext_vector_type(4)));

static __device__ __forceinline__ ushort f2h(float f) {
    _Float16 h = (_Float16)f;            // RNE
    ushort u; __builtin_memcpy(&u, &h, 2);
    return u;
}
static __device__ __forceinline__ float h2f(ushort u) {
    _Float16 h; __builtin_memcpy(&h, &u, 2);
    return (float)h;
}

// ---------------- convert x (f32 -> fp16) ----------------
__global__ __launch_bounds__(256) void convert_x_kernel(const float* __restrict__ x,
                                                        ushort* __restrict__ xh,
                                                        long total8) {
    long i = (long)blockIdx.x * 256 + threadIdx.x;
    long stride = (long)gridDim.x * 256;
    for (; i < total8; i += stride) {
        const float4* p = reinterpret_cast<const float4*>(x + i * 8);
        float4 a = p[0], b = p[1];
        uint4 o;
        o.x = (unsigned)f2h(a.x) | ((unsigned)f2h(a.y) << 16);
        o.y = (unsigned)f2h(a.z) | ((unsigned)f2h(a.w) << 16);
        o.z = (unsigned)f2h(b.x) | ((unsigned)f2h(b.y) << 16);
        o.w = (unsigned)f2h(b.z) | ((unsigned)f2h(b.w) << 16);
        *reinterpret_cast<uint4*>(xh + i * 8) = o;
    }
}

// ---------------- W1 -> W1T fp16  ([512][256] -> [256][512]) ----------------
__global__ __launch_bounds__(256) void convert_w1t_kernel(const float* __restrict__ W1,
                                                          ushort* __restrict__ w1t) {
    int k = blockIdx.x;      // 0..511
    int n = threadIdx.x;     // 0..255
    w1t[(size_t)n * NFEAT + k] = f2h(W1[(size_t)k * NHID + n]);
}

// ---------------- W2 transpose: W2T[40][256] <- W2[256][40] (f32) ----------------
__global__ __launch_bounds__(256) void transpose_w2_kernel(const float* __restrict__ W2,
                                                           float* __restrict__ W2T) {
    for (int i = threadIdx.x; i < NHID * NCLASS; i += 256) {
        int k = i / NCLASS, j = i - k * NCLASS;
        W2T[(size_t)j * NHID + k] = W2[i];
    }
}

// ---------------- gemm1 (MFMA fp16): suph = fp16( xh @ W1 ) ----------------
// 128x128 tile, BK=32, 4 waves (2x2), each wave 64x64 via 4x4 16x16x32 frags.
#define GM_BM 128
#define GM_BK 32

__global__ __launch_bounds__(256) void gemm1_mfma_kernel(const ushort* __restrict__ Ah,
                                                         const ushort* __restrict__ Bt,
                                                         ushort* __restrict__ Ch,
                                                         int M) {
    __shared__ ushort As[GM_BM * GM_BK];   // 8 KB, XOR-swizzled 16B slots
    __shared__ ushort Bs[GM_BM * GM_BK];   // 8 KB
    const int tid = threadIdx.x;
    const int wid = tid >> 6, lane = tid & 63;
    const int row0 = blockIdx.x * GM_BM;
    const int col0 = blockIdx.y * GM_BM;   // 0 or 128 (N=256)
    const int wr = (wid >> 1) * 64;
    const int wc = (wid & 1) * 64;
    const int l15 = lane & 15;
    const int lq  = lane >> 4;             // k-chunk 0..3

    const int sr = tid >> 2;               // staging row 0..63
    const int sc = tid & 3;                // staging 16B slot

    f32x4 acc[4][4] = {};

    for (int k0 = 0; k0 < NFEAT; k0 += GM_BK) {
        {
            int r0g = row0 + sr;
            int r1g = row0 + sr + 64;
            uint4 a0 = make_uint4(0, 0, 0, 0), a1 = make_uint4(0, 0, 0, 0);
            if (r0g < M) a0 = *reinterpret_cast<const uint4*>(&Ah[(size_t)r0g * NFEAT + k0 + sc * 8]);
            if (r1g < M) a1 = *reinterpret_cast<const uint4*>(&Ah[(size_t)r1g * NFEAT + k0 + sc * 8]);
            int sw0 = sc ^ ((sr ^ (sr >> 2)) & 3);
            int sw1 = sc ^ (((sr + 64) ^ ((sr + 64) >> 2)) & 3);
            *reinterpret_cast<uint4*>(&As[sr * GM_BK + sw0 * 8]) = a0;
            *reinterpret_cast<uint4*>(&As[(sr + 64) * GM_BK + sw1 * 8]) = a1;
            uint4 b0 = *reinterpret_cast<const uint4*>(&Bt[(size_t)(col0 + sr) * NFEAT + k0 + sc * 8]);
            uint4 b1v = *reinterpret_cast<const uint4*>(&Bt[(size_t)(col0 + sr + 64) * NFEAT + k0 + sc * 8]);
            *reinterpret_cast<uint4*>(&Bs[sr * GM_BK + sw0 * 8]) = b0;
            *reinterpret_cast<uint4*>(&Bs[(sr + 64) * GM_BK + sw1 * 8]) = b1v;
        }
        __syncthreads();
        f16x8 af[4], bfr[4];
        #pragma unroll
        for (int mi = 0; mi < 4; ++mi) {
            int r = wr + mi * 16 + l15;
            int sw = lq ^ ((r ^ (r >> 2)) & 3);
            af[mi] = *reinterpret_cast<const f16x8*>(&As[r * GM_BK + sw * 8]);
        }
        #pragma unroll
        for (int ni = 0; ni < 4; ++ni) {
            int c = wc + ni * 16 + l15;
            int sw = lq ^ ((c ^ (c >> 2)) & 3);
            bfr[ni] = *reinterpret_cast<const f16x8*>(&Bs[c * GM_BK + sw * 8]);
        }
        #pragma unroll
        for (int mi = 0; mi < 4; ++mi)
            #pragma unroll
            for (int ni = 0; ni < 4; ++ni)
                acc[mi][ni] = __builtin_amdgcn_mfma_f32_16x16x32_f16(af[mi], bfr[ni], acc[mi][ni], 0, 0, 0);
        __syncthreads();
    }
    // C/D layout: col = lane&15, row = (lane>>4)*4 + reg
    #pragma unroll
    for (int mi = 0; mi < 4; ++mi) {
        #pragma unroll
        for (int j = 0; j < 4; ++j) {
            int gr = row0 + wr + mi * 16 + lq * 4 + j;
            if (gr < M) {
                #pragma unroll
                for (int ni = 0; ni < 4; ++ni) {
                    Ch[(size_t)gr * NHID + col0 + wc + ni * 16 + l15] = f2h(acc[mi][ni][j]);
                }
            }
        }
    }
}

// ---------------- CSR build ----------------
__global__ __launch_bounds__(256) void hist_kernel(const int* __restrict__ dst,
                                                   int* __restrict__ deg, int E) {
    int e = blockIdx.x * 256 + threadIdx.x;
    if (e < E) atomicAdd(&deg[dst[e]], 1);
}

#define SCAN_CHUNK 1024
__global__ __launch_bounds__(256) void scan1_kernel(const int* __restrict__ deg,
                                                    int* __restrict__ part,
                                                    int* __restrict__ bsums, int N) {
    __shared__ int s[256];
    int b = blockIdx.x, t = threadIdx.x;
    int i0 = b * SCAN_CHUNK + t * 4;
    int d[4];
    #pragma unroll
    for (int u = 0; u < 4; ++u) d[u] = (i0 + u < N) ? deg[i0 + u] : 0;
    int loc = d[0] + d[1] + d[2] + d[3];
    s[t] = loc;
    __syncthreads();
    for (int off = 1; off < 256; off <<= 1) {
        int v = (t >= off) ? s[t - off] : 0;
        __syncthreads();
        s[t] += v;
        __syncthreads();
    }
    int run = s[t] - loc;
    #pragma unroll
    for (int u = 0; u < 4; ++u) {
        if (i0 + u < N) part[i0 + u] = run;
        run += d[u];
    }
    if (t == 255) bsums[b] = s[255];
}

__global__ __launch_bounds__(128) void scan2_kernel(int* __restrict__ bsums, int nb) {
    __shared__ int s[128];
    int t = threadIdx.x;
    int v = (t < nb) ? bsums[t] : 0;
    s[t] = v;
    __syncthreads();
    for (int off = 1; off < 128; off <<= 1) {
        int x = (t >= off) ? s[t - off] : 0;
        __syncthreads();
        s[t] += x;
        __syncthreads();
    }
    if (t < nb) bsums[t] = s[t] - v;
}

__global__ __launch_bounds__(256) void scan3_kernel(int* __restrict__ row_start,
                                                    const int* __restrict__ bsums,
                                                    int N, int E) {
    int b = blockIdx.x, t = threadIdx.x;
    int i0 = b * SCAN_CHUNK + t * 4;
    int add = bsums[b];
    #pragma unroll
    for (int u = 0; u < 4; ++u)
        if (i0 + u < N) row_start[i0 + u] += add;
    if (b == 0 && t == 0) row_start[N] = E;
}

__global__ __launch_bounds__(256) void scatter_kernel(const int* __restrict__ src,
                                                      const int* __restrict__ dst,
                                                      const float* __restrict__ w,
                                                      int* __restrict__ cursor,
                                                      int2* __restrict__ csr, int E) {
    int e = blockIdx.x * 256 + threadIdx.x;
    if (e >= E) return;
    int d = dst[e];
    int pos = atomicAdd(&cursor[d], 1);
    csr[pos] = make_int2(src[e], __float_as_int(w[e]));
}

// ---------------- conv1: c2[n] = relu( (A @ suph)[n] + b1 ) @ W2 ----------------
// One block per dst node. fp16 gather, 2 edges per wave-instr:
// lanes 0-31 -> even edge of pair, 32-63 -> odd; lane owns feats (lane&31)*8..+7.
#define C1_CHUNK 256
__global__ __launch_bounds__(256) void conv1_kernel(const int2* __restrict__ csr,
                                                    const int* __restrict__ row_start,
                                                    const ushort* __restrict__ suph,
                                                    const float* __restrict__ b1,
                                                    const float* __restrict__ w2t,
                                                    float* __restrict__ c2, int N) {
    __shared__ int2  eb[C1_CHUNK + 1];
    __shared__ float pacc[4][NHID];
    __shared__ float hrow[NHID];
    __shared__ float pbuf[160];
    const int n = blockIdx.x;
    const int t = threadIdx.x;
    const int wave = t >> 6;
    const int lane = t & 63;
    const int half = lane >> 5;
    const int fl   = lane & 31;
    const int start = row_start[n], end = row_start[n + 1];

    float acc[8] = {};
    for (int c0 = start; c0 < end; c0 += C1_CHUNK) {
        int clen = min(C1_CHUNK, end - c0);
        __syncthreads();
        if (t < clen) eb[t] = csr[c0 + t];
        if (t == 0 && (clen & 1)) eb[clen] = make_int2(0, 0);   // zero-weight pad
        __syncthreads();
        int npairs = (clen + 1) >> 1;
        int p = wave;
        for (; p + 4 < npairs; p += 8) {
            int2 eA = eb[2 * p + half];
            int2 eB = eb[2 * (p + 4) + half];
            uint4 vA = *reinterpret_cast<const uint4*>(&suph[(size_t)eA.x * NHID + fl * 8]);
            uint4 vB = *reinterpret_cast<const uint4*>(&suph[(size_t)eB.x * NHID + fl * 8]);
            float wA = __int_as_float(eA.y), wB = __int_as_float(eB.y);
            acc[0] += wA * h2f((ushort)(vA.x & 0xffff)) + wB * h2f((ushort)(vB.x & 0xffff));
            acc[1] += wA * h2f((ushort)(vA.x >> 16))    + wB * h2f((ushort)(vB.x >> 16));
            acc[2] += wA * h2f((ushort)(vA.y & 0xffff)) + wB * h2f((ushort)(vB.y & 0xffff));
            acc[3] += wA * h2f((ushort)(vA.y >> 16))    + wB * h2f((ushort)(vB.y >> 16));
            acc[4] += wA * h2f((ushort)(vA.z & 0xffff)) + wB * h2f((ushort)(vB.z & 0xffff));
            acc[5] += wA * h2f((ushort)(vA.z >> 16))    + wB * h2f((ushort)(vB.z >> 16));
            acc[6] += wA * h2f((ushort)(vA.w & 0xffff)) + wB * h2f((ushort)(vB.w & 0xffff));
            acc[7] += wA * h2f((ushort)(vA.w >> 16))    + wB * h2f((ushort)(vB.w >> 16));
        }
        for (; p < npairs; p += 4) {
            int2 eA = eb[2 * p + half];
            uint4 vA = *reinterpret_cast<const uint4*>(&suph[(size_t)eA.x * NHID + fl * 8]);
            float wA = __int_as_float(eA.y);
            acc[0] += wA * h2f((ushort)(vA.x & 0xffff));
            acc[1] += wA * h2f((ushort)(vA.x >> 16));
            acc[2] += wA * h2f((ushort)(vA.y & 0xffff));
            acc[3] += wA * h2f((ushort)(vA.y >> 16));
            acc[4] += wA * h2f((ushort)(vA.z & 0xffff));
            acc[5] += wA * h2f((ushort)(vA.z >> 16));
            acc[6] += wA * h2f((ushort)(vA.w & 0xffff));
            acc[7] += wA * h2f((ushort)(vA.w >> 16));
        }
    }
    #pragma unroll
    for (int i = 0; i < 8; ++i) acc[i] += __shfl_xor(acc[i], 32, 64);
    if (half == 0) {
        *reinterpret_cast<float4*>(&pacc[wave][fl * 8])     = make_float4(acc[0], acc[1], acc[2], acc[3]);
        *reinterpret_cast<float4*>(&pacc[wave][fl * 8 + 4]) = make_float4(acc[4], acc[5], acc[6], acc[7]);
    }
    __syncthreads();
    hrow[t] = fmaxf(pacc[0][t] + pacc[1][t] + pacc[2][t] + pacc[3][t] + b1[t], 0.f);
    __syncthreads();
    if (t < 160) {
        int jc = t % 40, q = t / 40;
        const float4* hp = reinterpret_cast<const float4*>(&hrow[q * 64]);
        const float4* wp = reinterpret_cast<const float4*>(&w2t[(size_t)jc * NHID + q * 64]);
        float p = 0.f;
        #pragma unroll
        for (int kk = 0; kk < 16; ++kk) {
            float4 h4 = hp[kk];
            float4 w4 = wp[kk];
            p += h4.x * w4.x + h4.y * w4.y + h4.z * w4.z + h4.w * w4.w;
        }
        pbuf[t] = p;
    }
    __syncthreads();
    if (t < NCLASS) {
        c2[(size_t)n * NCLASS + t] = pbuf[t] + pbuf[t + 40] + pbuf[t + 80] + pbuf[t + 120];
    }
}

// ---------------- conv2: out[n] = softmax( (A @ c2)[n] ) ----------------
__global__ __launch_bounds__(256) void conv2_kernel(const int2* __restrict__ csr,
                                                    const int* __restrict__ row_start,
                                                    const float* __restrict__ c2,
                                                    float* __restrict__ out, int N) {
    int wave = threadIdx.x >> 6;
    int lane = threadIdx.x & 63;
    int n = blockIdx.x * 4 + wave;
    if (n >= N) return;
    int start = row_start[n], end = row_start[n + 1];
    bool act = lane < NCLASS;
    float acc = 0.f;
    int j = start;
    for (; j + 7 < end; j += 8) {
        int2 e0 = csr[j];
        int2 e1 = csr[j + 1];
        int2 e2 = csr[j + 2];
        int2 e3 = csr[j + 3];
        int2 e4 = csr[j + 4];
        int2 e5 = csr[j + 5];
        int2 e6 = csr[j + 6];
        int2 e7 = csr[j + 7];
        if (act) {
            float s0 = c2[(size_t)e0.x * NCLASS + lane];
            float s1 = c2[(size_t)e1.x * NCLASS + lane];
            float s2 = c2[(size_t)e2.x * NCLASS + lane];
            float s3 = c2[(size_t)e3.x * NCLASS + lane];
            float s4 = c2[(size_t)e4.x * NCLASS + lane];
            float s5 = c2[(size_t)e5.x * NCLASS + lane];
            float s6 = c2[(size_t)e6.x * NCLASS + lane];
            float s7 = c2[(size_t)e7.x * NCLASS + lane];
            acc += __int_as_float(e0.y) * s0 + __int_as_float(e1.y) * s1
                 + __int_as_float(e2.y) * s2 + __int_as_float(e3.y) * s3
                 + __int_as_float(e4.y) * s4 + __int_as_float(e5.y) * s5
                 + __int_as_float(e6.y) * s6 + __int_as_float(e7.y) * s7;
        }
    }
    for (; j < end; ++j) {
        int2 e0 = csr[j];
        if (act) acc += __int_as_float(e0.y) * c2[(size_t)e0.x * NCLASS + lane];
    }
    float m = act ? acc : -INFINITY;
    #pragma unroll
    for (int off = 32; off > 0; off >>= 1) m = fmaxf(m, __shfl_xor(m, off, 64));
    float e = act ? expf(acc - m) : 0.f;
    float s = e;
    #pragma unroll
    for (int off = 32; off > 0; off >>= 1) s += __shfl_xor(s, off, 64);
    if (act) out[(size_t)n * NCLASS + lane] = e / s;
}

extern "C" void kernel_launch(void* const* d_in, const int* in_sizes, int n_in,
                              void* d_out, int out_size, void* d_ws, size_t ws_size,
                              hipStream_t stream) {
    const float* x  = (const float*)d_in[0];
    const int*   ei = (const int*)d_in[1];
    const float* ew = (const float*)d_in[2];
    const float* W1 = (const float*)d_in[3];
    const float* b1 = (const float*)d_in[4];
    const float* W2 = (const float*)d_in[5];
    float* out = (float*)d_out;

    const int M = in_sizes[0] / NFEAT;       // 100000
    const int E = in_sizes[1] / 2;           // 3200000
    const int* src = ei;
    const int* dst = ei + E;

    // workspace layout (~196 MB)
    char* ws = (char*)d_ws;
    ushort* xh      = (ushort*)ws;                                  // M*512 fp16 = 102.4 MB
    ushort* suph    = xh + (size_t)M * NFEAT;                       // M*256 fp16 = 51.2 MB
    float*  c2      = (float*)(suph + (size_t)M * NHID);            // M*40 f32   = 16 MB
    int2*   csr     = (int2*)(c2 + (size_t)M * NCLASS);             // E int2     = 25.6 MB
    int*    deg     = (int*)(csr + E);                              // M
    int*    row_start = deg + M;                                    // M+1
    int*    cursor  = row_start + (M + 1);                          // M
    int*    bsums   = cursor + M;                                   // 128
    float*  w2t     = (float*)(bsums + 128);                        // 40*256 f32
    ushort* w1t     = (ushort*)(w2t + NCLASS * NHID);               // 256*512 fp16

    const int nscan = (M + SCAN_CHUNK - 1) / SCAN_CHUNK;

    // ---- converts + CSR build ----
    convert_x_kernel<<<2048, 256, 0, stream>>>(x, xh, (long)M * NFEAT / 8);
    convert_w1t_kernel<<<NFEAT, 256, 0, stream>>>(W1, w1t);
    transpose_w2_kernel<<<1, 256, 0, stream>>>(W2, w2t);

    hipMemsetAsync(deg, 0, (size_t)M * 4, stream);
    hist_kernel<<<(E + 255) / 256, 256, 0, stream>>>(dst, deg, E);
    scan1_kernel<<<nscan, 256, 0, stream>>>(deg, row_start, bsums, M);
    scan2_kernel<<<1, 128, 0, stream>>>(bsums, nscan);
    scan3_kernel<<<nscan, 256, 0, stream>>>(row_start, bsums, M, E);
    hipMemcpyAsync(cursor, row_start, (size_t)M * 4, hipMemcpyDeviceToDevice, stream);
    scatter_kernel<<<(E + 255) / 256, 256, 0, stream>>>(src, dst, ew, cursor, csr, E);

    // ---- dense + sparse pipeline ----
    dim3 g1((M + GM_BM - 1) / GM_BM, NHID / GM_BM);
    gemm1_mfma_kernel<<<g1, 256, 0, stream>>>(xh, w1t, suph, M);

    conv1_kernel<<<M, 256, 0, stream>>>(csr, row_start, suph, b1, w2t, c2, M);
    conv2_kernel<<<(M + 3) / 4, 256, 0, stream>>>(csr, row_start, c2, out, M);
}

// Round 7
// 1126.183 us; speedup vs baseline: 11.7246x; 1.0766x over previous
//
#include <hip/hip_runtime.h>
#include <hip/hip_bf16.h>
#include <math.h>

// GCN forward: softmax( A * relu(A*(x@W1)+b1) @ W2 )
// N=100000 nodes, E=3.2M edges, F 512->256->40.
// CSR (dst-sorted) built on device -> gather SpMM, no atomics in hot path.
// support1 kept in FP16 (51 MB) -> conv1 gathers half the bytes; fp16 (not
// bf16) keeps absmax ~8x lower. gemm1 = fp16 MFMA with fused f32->fp16
// conversion of x in the staging path. gemm2 fused into conv1 epilogue;
// softmax fused into conv2. conv1 runs a 4-deep gather pipeline.

#define NFEAT 512
#define NHID  256
#define NCLASS 40

typedef _Float16 f16x8 __attribute__((ext_vector_type(8)));
typedef float    f32x4 __attribute__((ext_vector_type(4)));

static __device__ __forceinline__ ushort f2h(float f) {
    _Float16 h = (_Float16)f;            // RNE
    ushort u; __builtin_memcpy(&u, &h, 2);
    return u;
}
static __device__ __forceinline__ float h2f(ushort u) {
    _Float16 h; __builtin_memcpy(&h, &u, 2);
    return (float)h;
}
static __device__ __forceinline__ float hlo(unsigned u) { return h2f((ushort)(u & 0xffff)); }
static __device__ __forceinline__ float hhi(unsigned u) { return h2f((ushort)(u >> 16)); }

static __device__ __forceinline__ uint4 pack8(float4 lo, float4 hi) {
    uint4 o;
    o.x = (unsigned)f2h(lo.x) | ((unsigned)f2h(lo.y) << 16);
    o.y = (unsigned)f2h(lo.z) | ((unsigned)f2h(lo.w) << 16);
    o.z = (unsigned)f2h(hi.x) | ((unsigned)f2h(hi.y) << 16);
    o.w = (unsigned)f2h(hi.z) | ((unsigned)f2h(hi.w) << 16);
    return o;
}

// ---------------- W1 -> W1T fp16  ([512][256] -> [256][512]) ----------------
__global__ __launch_bounds__(256) void convert_w1t_kernel(const float* __restrict__ W1,
                                                          ushort* __restrict__ w1t) {
    int k = blockIdx.x;      // 0..511
    int n = threadIdx.x;     // 0..255
    w1t[(size_t)n * NFEAT + k] = f2h(W1[(size_t)k * NHID + n]);
}

// ---------------- W2 transpose: W2T[40][256] <- W2[256][40] (f32) ----------------
__global__ __launch_bounds__(256) void transpose_w2_kernel(const float* __restrict__ W2,
                                                           float* __restrict__ W2T) {
    for (int i = threadIdx.x; i < NHID * NCLASS; i += 256) {
        int k = i / NCLASS, j = i - k * NCLASS;
        W2T[(size_t)j * NHID + k] = W2[i];
    }
}

// ---------------- gemm1 (MFMA fp16): suph = fp16( x @ W1 ), x converted inline ----
// 128x128 tile, BK=32, 4 waves (2x2), each wave 64x64 via 4x4 16x16x32 frags.
#define GM_BM 128
#define GM_BK 32

__global__ __launch_bounds__(256) void gemm1_mfma_kernel(const float* __restrict__ A,
                                                         const ushort* __restrict__ Bt,
                                                         ushort* __restrict__ Ch,
                                                         int M) {
    __shared__ ushort As[GM_BM * GM_BK];   // 8 KB, XOR-swizzled 16B slots
    __shared__ ushort Bs[GM_BM * GM_BK];   // 8 KB
    const int tid = threadIdx.x;
    const int wid = tid >> 6, lane = tid & 63;
    const int row0 = blockIdx.x * GM_BM;
    const int col0 = blockIdx.y * GM_BM;   // 0 or 128 (N=256)
    const int wr = (wid >> 1) * 64;
    const int wc = (wid & 1) * 64;
    const int l15 = lane & 15;
    const int lq  = lane >> 4;             // k-chunk 0..3

    const int sr = tid >> 2;               // staging row 0..63
    const int sc = tid & 3;                // staging 16B slot (8 fp16 / 32B f32)

    f32x4 acc[4][4] = {};

    for (int k0 = 0; k0 < NFEAT; k0 += GM_BK) {
        {
            int r0g = row0 + sr;
            int r1g = row0 + sr + 64;
            uint4 a0 = make_uint4(0, 0, 0, 0), a1 = make_uint4(0, 0, 0, 0);
            if (r0g < M) {
                const float4* p = reinterpret_cast<const float4*>(&A[(size_t)r0g * NFEAT + k0 + sc * 8]);
                a0 = pack8(p[0], p[1]);
            }
            if (r1g < M) {
                const float4* p = reinterpret_cast<const float4*>(&A[(size_t)r1g * NFEAT + k0 + sc * 8]);
                a1 = pack8(p[0], p[1]);
            }
            int sw0 = sc ^ ((sr ^ (sr >> 2)) & 3);
            int sw1 = sc ^ (((sr + 64) ^ ((sr + 64) >> 2)) & 3);
            *reinterpret_cast<uint4*>(&As[sr * GM_BK + sw0 * 8]) = a0;
            *reinterpret_cast<uint4*>(&As[(sr + 64) * GM_BK + sw1 * 8]) = a1;
            uint4 b0 = *reinterpret_cast<const uint4*>(&Bt[(size_t)(col0 + sr) * NFEAT + k0 + sc * 8]);
            uint4 b1v = *reinterpret_cast<const uint4*>(&Bt[(size_t)(col0 + sr + 64) * NFEAT + k0 + sc * 8]);
            *reinterpret_cast<uint4*>(&Bs[sr * GM_BK + sw0 * 8]) = b0;
            *reinterpret_cast<uint4*>(&Bs[(sr + 64) * GM_BK + sw1 * 8]) = b1v;
        }
        __syncthreads();
        f16x8 af[4], bfr[4];
        #pragma unroll
        for (int mi = 0; mi < 4; ++mi) {
            int r = wr + mi * 16 + l15;
            int sw = lq ^ ((r ^ (r >> 2)) & 3);
            af[mi] = *reinterpret_cast<const f16x8*>(&As[r * GM_BK + sw * 8]);
        }
        #pragma unroll
        for (int ni = 0; ni < 4; ++ni) {
            int c = wc + ni * 16 + l15;
            int sw = lq ^ ((c ^ (c >> 2)) & 3);
            bfr[ni] = *reinterpret_cast<const f16x8*>(&Bs[c * GM_BK + sw * 8]);
        }
        #pragma unroll
        for (int mi = 0; mi < 4; ++mi)
            #pragma unroll
            for (int ni = 0; ni < 4; ++ni)
                acc[mi][ni] = __builtin_amdgcn_mfma_f32_16x16x32_f16(af[mi], bfr[ni], acc[mi][ni], 0, 0, 0);
        __syncthreads();
    }
    // C/D layout: col = lane&15, row = (lane>>4)*4 + reg
    #pragma unroll
    for (int mi = 0; mi < 4; ++mi) {
        #pragma unroll
        for (int j = 0; j < 4; ++j) {
            int gr = row0 + wr + mi * 16 + lq * 4 + j;
            if (gr < M) {
                #pragma unroll
                for (int ni = 0; ni < 4; ++ni) {
                    Ch[(size_t)gr * NHID + col0 + wc + ni * 16 + l15] = f2h(acc[mi][ni][j]);
                }
            }
        }
    }
}

// ---------------- CSR build ----------------
__global__ __launch_bounds__(256) void hist_kernel(const int* __restrict__ dst,
                                                   int* __restrict__ deg, int E) {
    int e = blockIdx.x * 256 + threadIdx.x;
    if (e < E) atomicAdd(&deg[dst[e]], 1);
}

#define SCAN_CHUNK 1024
__global__ __launch_bounds__(256) void scan1_kernel(const int* __restrict__ deg,
                                                    int* __restrict__ part,
                                                    int* __restrict__ bsums, int N) {
    __shared__ int s[256];
    int b = blockIdx.x, t = threadIdx.x;
    int i0 = b * SCAN_CHUNK + t * 4;
    int d[4];
    #pragma unroll
    for (int u = 0; u < 4; ++u) d[u] = (i0 + u < N) ? deg[i0 + u] : 0;
    int loc = d[0] + d[1] + d[2] + d[3];
    s[t] = loc;
    __syncthreads();
    for (int off = 1; off < 256; off <<= 1) {
        int v = (t >= off) ? s[t - off] : 0;
        __syncthreads();
        s[t] += v;
        __syncthreads();
    }
    int run = s[t] - loc;
    #pragma unroll
    for (int u = 0; u < 4; ++u) {
        if (i0 + u < N) part[i0 + u] = run;
        run += d[u];
    }
    if (t == 255) bsums[b] = s[255];
}

__global__ __launch_bounds__(128) void scan2_kernel(int* __restrict__ bsums, int nb) {
    __shared__ int s[128];
    int t = threadIdx.x;
    int v = (t < nb) ? bsums[t] : 0;
    s[t] = v;
    __syncthreads();
    for (int off = 1; off < 128; off <<= 1) {
        int x = (t >= off) ? s[t - off] : 0;
        __syncthreads();
        s[t] += x;
        __syncthreads();
    }
    if (t < nb) bsums[t] = s[t] - v;
}

__global__ __launch_bounds__(256) void scan3_kernel(int* __restrict__ row_start,
                                                    const int* __restrict__ bsums,
                                                    int N, int E) {
    int b = blockIdx.x, t = threadIdx.x;
    int i0 = b * SCAN_CHUNK + t * 4;
    int add = bsums[b];
    #pragma unroll
    for (int u = 0; u < 4; ++u)
        if (i0 + u < N) row_start[i0 + u] += add;
    if (b == 0 && t == 0) row_start[N] = E;
}

__global__ __launch_bounds__(256) void scatter_kernel(const int* __restrict__ src,
                                                      const int* __restrict__ dst,
                                                      const float* __restrict__ w,
                                                      int* __restrict__ cursor,
                                                      int2* __restrict__ csr, int E) {
    int e = blockIdx.x * 256 + threadIdx.x;
    if (e >= E) return;
    int d = dst[e];
    int pos = atomicAdd(&cursor[d], 1);
    csr[pos] = make_int2(src[e], __float_as_int(w[e]));
}

// ---------------- conv1: c2[n] = relu( (A @ suph)[n] + b1 ) @ W2 ----------------
// One block per dst node. fp16 gather, 2 edges per wave-instr:
// lanes 0-31 -> even edge of pair, 32-63 -> odd; lane owns feats (lane&31)*8..+7.
// 4-deep load pipeline: pairs p, p+4, p+8, p+12 in flight per iteration.
#define C1_CHUNK 256
__global__ __launch_bounds__(256) void conv1_kernel(const int2* __restrict__ csr,
                                                    const int* __restrict__ row_start,
                                                    const ushort* __restrict__ suph,
                                                    const float* __restrict__ b1,
                                                    const float* __restrict__ w2t,
                                                    float* __restrict__ c2, int N) {
    __shared__ int2  eb[C1_CHUNK + 1];
    __shared__ float pacc[4][NHID];
    __shared__ float hrow[NHID];
    __shared__ float pbuf[160];
    const int n = blockIdx.x;
    const int t = threadIdx.x;
    const int wave = t >> 6;
    const int lane = t & 63;
    const int half = lane >> 5;
    const int fl   = lane & 31;
    const int start = row_start[n], end = row_start[n + 1];

    float acc[8] = {};
    for (int c0 = start; c0 < end; c0 += C1_CHUNK) {
        int clen = min(C1_CHUNK, end - c0);
        __syncthreads();
        if (t < clen) eb[t] = csr[c0 + t];
        if (t == 0 && (clen & 1)) eb[clen] = make_int2(0, 0);   // zero-weight pad
        __syncthreads();
        int npairs = (clen + 1) >> 1;
        int p = wave;
        for (; p + 12 < npairs; p += 16) {
            int2 eA = eb[2 * p + half];
            int2 eB = eb[2 * (p + 4) + half];
            int2 eC = eb[2 * (p + 8) + half];
            int2 eD = eb[2 * (p + 12) + half];
            uint4 vA = *reinterpret_cast<const uint4*>(&suph[(size_t)eA.x * NHID + fl * 8]);
            uint4 vB = *reinterpret_cast<const uint4*>(&suph[(size_t)eB.x * NHID + fl * 8]);
            uint4 vC = *reinterpret_cast<const uint4*>(&suph[(size_t)eC.x * NHID + fl * 8]);
            uint4 vD = *reinterpret_cast<const uint4*>(&suph[(size_t)eD.x * NHID + fl * 8]);
            float wA = __int_as_float(eA.y), wB = __int_as_float(eB.y);
            float wC = __int_as_float(eC.y), wD = __int_as_float(eD.y);
            acc[0] += wA * hlo(vA.x) + wB * hlo(vB.x) + wC * hlo(vC.x) + wD * hlo(vD.x);
            acc[1] += wA * hhi(vA.x) + wB * hhi(vB.x) + wC * hhi(vC.x) + wD * hhi(vD.x);
            acc[2] += wA * hlo(vA.y) + wB * hlo(vB.y) + wC * hlo(vC.y) + wD * hlo(vD.y);
            acc[3] += wA * hhi(vA.y) + wB * hhi(vB.y) + wC * hhi(vC.y) + wD * hhi(vD.y);
            acc[4] += wA * hlo(vA.z) + wB * hlo(vB.z) + wC * hlo(vC.z) + wD * hlo(vD.z);
            acc[5] += wA * hhi(vA.z) + wB * hhi(vB.z) + wC * hhi(vC.z) + wD * hhi(vD.z);
            acc[6] += wA * hlo(vA.w) + wB * hlo(vB.w) + wC * hlo(vC.w) + wD * hlo(vD.w);
            acc[7] += wA * hhi(vA.w) + wB * hhi(vB.w) + wC * hhi(vC.w) + wD * hhi(vD.w);
        }
        for (; p + 4 < npairs; p += 8) {
            int2 eA = eb[2 * p + half];
            int2 eB = eb[2 * (p + 4) + half];
            uint4 vA = *reinterpret_cast<const uint4*>(&suph[(size_t)eA.x * NHID + fl * 8]);
            uint4 vB = *reinterpret_cast<const uint4*>(&suph[(size_t)eB.x * NHID + fl * 8]);
            float wA = __int_as_float(eA.y), wB = __int_as_float(eB.y);
            acc[0] += wA * hlo(vA.x) + wB * hlo(vB.x);
            acc[1] += wA * hhi(vA.x) + wB * hhi(vB.x);
            acc[2] += wA * hlo(vA.y) + wB * hlo(vB.y);
            acc[3] += wA * hhi(vA.y) + wB * hhi(vB.y);
            acc[4] += wA * hlo(vA.z) + wB * hlo(vB.z);
            acc[5] += wA * hhi(vA.z) + wB * hhi(vB.z);
            acc[6] += wA * hlo(vA.w) + wB * hlo(vB.w);
            acc[7] += wA * hhi(vA.w) + wB * hhi(vB.w);
        }
        for (; p < npairs; p += 4) {
            int2 eA = eb[2 * p + half];
            uint4 vA = *reinterpret_cast<const uint4*>(&suph[(size_t)eA.x * NHID + fl * 8]);
            float wA = __int_as_float(eA.y);
            acc[0] += wA * hlo(vA.x);
            acc[1] += wA * hhi(vA.x);
            acc[2] += wA * hlo(vA.y);
            acc[3] += wA * hhi(vA.y);
            acc[4] += wA * hlo(vA.z);
            acc[5] += wA * hhi(vA.z);
            acc[6] += wA * hlo(vA.w);
            acc[7] += wA * hhi(vA.w);
        }
    }
    #pragma unroll
    for (int i = 0; i < 8; ++i) acc[i] += __shfl_xor(acc[i], 32, 64);
    if (half == 0) {
        *reinterpret_cast<float4*>(&pacc[wave][fl * 8])     = make_float4(acc[0], acc[1], acc[2], acc[3]);
        *reinterpret_cast<float4*>(&pacc[wave][fl * 8 + 4]) = make_float4(acc[4], acc[5], acc[6], acc[7]);
    }
    __syncthreads();
    hrow[t] = fmaxf(pacc[0][t] + pacc[1][t] + pacc[2][t] + pacc[3][t] + b1[t], 0.f);
    __syncthreads();
    if (t < 160) {
        int jc = t % 40, q = t / 40;
        const float4* hp = reinterpret_cast<const float4*>(&hrow[q * 64]);
        const float4* wp = reinterpret_cast<const float4*>(&w2t[(size_t)jc * NHID + q * 64]);
        float p = 0.f;
        #pragma unroll
        for (int kk = 0; kk < 16; ++kk) {
            float4 h4 = hp[kk];
            float4 w4 = wp[kk];
            p += h4.x * w4.x + h4.y * w4.y + h4.z * w4.z + h4.w * w4.w;
        }
        pbuf[t] = p;
    }
    __syncthreads();
    if (t < NCLASS) {
        c2[(size_t)n * NCLASS + t] = pbuf[t] + pbuf[t + 40] + pbuf[t + 80] + pbuf[t + 120];
    }
}

// ---------------- conv2: out[n] = softmax( (A @ c2)[n] ) ----------------
// one wave per dst node; lanes 0..39 own classes; 16 edges in flight.
__global__ __launch_bounds__(256) void conv2_kernel(const int2* __restrict__ csr,
                                                    const int* __restrict__ row_start,
                                                    const float* __restrict__ c2,
                                                    float* __restrict__ out, int N) {
    int wave = threadIdx.x >> 6;
    int lane = threadIdx.x & 63;
    int n = blockIdx.x * 4 + wave;
    if (n >= N) return;
    int start = row_start[n], end = row_start[n + 1];
    bool act = lane < NCLASS;
    float acc = 0.f;
    int j = start;
    for (; j + 15 < end; j += 16) {
        int2 ee[16];
        #pragma unroll
        for (int u = 0; u < 16; ++u) ee[u] = csr[j + u];
        if (act) {
            float sv[16];
            #pragma unroll
            for (int u = 0; u < 16; ++u) sv[u] = c2[(size_t)ee[u].x * NCLASS + lane];
            #pragma unroll
            for (int u = 0; u < 16; ++u) acc += __int_as_float(ee[u].y) * sv[u];
        }
    }
    for (; j + 3 < end; j += 4) {
        int2 ee[4];
        #pragma unroll
        for (int u = 0; u < 4; ++u) ee[u] = csr[j + u];
        if (act) {
            float sv[4];
            #pragma unroll
            for (int u = 0; u < 4; ++u) sv[u] = c2[(size_t)ee[u].x * NCLASS + lane];
            #pragma unroll
            for (int u = 0; u < 4; ++u) acc += __int_as_float(ee[u].y) * sv[u];
        }
    }
    for (; j < end; ++j) {
        int2 e0 = csr[j];
        if (act) acc += __int_as_float(e0.y) * c2[(size_t)e0.x * NCLASS + lane];
    }
    float m = act ? acc : -INFINITY;
    #pragma unroll
    for (int off = 32; off > 0; off >>= 1) m = fmaxf(m, __shfl_xor(m, off, 64));
    float e = act ? expf(acc - m) : 0.f;
    float s = e;
    #pragma unroll
    for (int off = 32; off > 0; off >>= 1) s += __shfl_xor(s, off, 64);
    if (act) out[(size_t)n * NCLASS + lane] = e / s;
}

extern "C" void kernel_launch(void* const* d_in, const int* in_sizes, int n_in,
                              void* d_out, int out_size, void* d_ws, size_t ws_size,
                              hipStream_t stream) {
    const float* x  = (const float*)d_in[0];
    const int*   ei = (const int*)d_in[1];
    const float* ew = (const float*)d_in[2];
    const float* W1 = (const float*)d_in[3];
    const float* b1 = (const float*)d_in[4];
    const float* W2 = (const float*)d_in[5];
    float* out = (float*)d_out;

    const int M = in_sizes[0] / NFEAT;       // 100000
    const int E = in_sizes[1] / 2;           // 3200000
    const int* src = ei;
    const int* dst = ei + E;

    // workspace layout (~94 MB)
    char* ws = (char*)d_ws;
    ushort* suph    = (ushort*)ws;                                  // M*256 fp16 = 51.2 MB
    float*  c2      = (float*)(suph + (size_t)M * NHID);            // M*40 f32   = 16 MB
    int2*   csr     = (int2*)(c2 + (size_t)M * NCLASS);             // E int2     = 25.6 MB
    int*    deg     = (int*)(csr + E);                              // M
    int*    row_start = deg + M;                                    // M+1
    int*    cursor  = row_start + (M + 1);                          // M
    int*    bsums   = cursor + M;                                   // 128
    float*  w2t     = (float*)(bsums + 128);                        // 40*256 f32
    ushort* w1t     = (ushort*)(w2t + NCLASS * NHID);               // 256*512 fp16

    const int nscan = (M + SCAN_CHUNK - 1) / SCAN_CHUNK;

    // ---- converts + CSR build ----
    convert_w1t_kernel<<<NFEAT, 256, 0, stream>>>(W1, w1t);
    transpose_w2_kernel<<<1, 256, 0, stream>>>(W2, w2t);

    hipMemsetAsync(deg, 0, (size_t)M * 4, stream);
    hist_kernel<<<(E + 255) / 256, 256, 0, stream>>>(dst, deg, E);
    scan1_kernel<<<nscan, 256, 0, stream>>>(deg, row_start, bsums, M);
    scan2_kernel<<<1, 128, 0, stream>>>(bsums, nscan);
    scan3_kernel<<<nscan, 256, 0, stream>>>(row_start, bsums, M, E);
    hipMemcpyAsync(cursor, row_start, (size_t)M * 4, hipMemcpyDeviceToDevice, stream);
    scatter_kernel<<<(E + 255) / 256, 256, 0, stream>>>(src, dst, ew, cursor, csr, E);

    // ---- dense + sparse pipeline ----
    dim3 g1((M + GM_BM - 1) / GM_BM, NHID / GM_BM);
    gemm1_mfma_kernel<<<g1, 256, 0, stream>>>(x, w1t, suph, M);

    conv1_kernel<<<M, 256, 0, stream>>>(csr, row_start, suph, b1, w2t, c2, M);
    conv2_kernel<<<(M + 3) / 4, 256, 0, stream>>>(csr, row_start, c2, out, M);
}

// Round 8
// 1116.778 us; speedup vs baseline: 11.8233x; 1.0084x over previous
//
#include <hip/hip_runtime.h>
#include <hip/hip_bf16.h>
#include <math.h>

// GCN forward: softmax( A * relu(A*(x@W1)+b1) @ W2 )
// N=100000 nodes, E=3.2M edges, F 512->256->40.
// CSR (dst-sorted) built on device -> gather SpMM, no atomics in hot path.
// conv1: ONE WAVE PER NODE, no barriers, 8-deep gather pipeline, edges
// distributed by __shfl; __launch_bounds__(256,4) so VGPRs (not 36!) allow
// real MLP. support1 in FP16 (51 MB). gemm1 = fp16 MFMA w/ fused convert.

#define NFEAT 512
#define NHID  256
#define NCLASS 40

typedef _Float16 f16x8 __attribute__((ext_vector_type(8)));
typedef float    f32x4 __attribute__((ext_vector_type(4)));

static __device__ __forceinline__ ushort f2h(float f) {
    _Float16 h = (_Float16)f;            // RNE
    ushort u; __builtin_memcpy(&u, &h, 2);
    return u;
}
static __device__ __forceinline__ float h2f(ushort u) {
    _Float16 h; __builtin_memcpy(&h, &u, 2);
    return (float)h;
}
static __device__ __forceinline__ float hlo(unsigned u) { return h2f((ushort)(u & 0xffff)); }
static __device__ __forceinline__ float hhi(unsigned u) { return h2f((ushort)(u >> 16)); }

static __device__ __forceinline__ uint4 pack8(float4 lo, float4 hi) {
    uint4 o;
    o.x = (unsigned)f2h(lo.x) | ((unsigned)f2h(lo.y) << 16);
    o.y = (unsigned)f2h(lo.z) | ((unsigned)f2h(lo.w) << 16);
    o.z = (unsigned)f2h(hi.x) | ((unsigned)f2h(hi.y) << 16);
    o.w = (unsigned)f2h(hi.z) | ((unsigned)f2h(hi.w) << 16);
    return o;
}

// ---------------- W1 -> W1T fp16  ([512][256] -> [256][512]) ----------------
__global__ __launch_bounds__(256) void convert_w1t_kernel(const float* __restrict__ W1,
                                                          ushort* __restrict__ w1t) {
    int k = blockIdx.x;      // 0..511
    int n = threadIdx.x;     // 0..255
    w1t[(size_t)n * NFEAT + k] = f2h(W1[(size_t)k * NHID + n]);
}

// ---------------- W2 transpose: W2T[40][256] <- W2[256][40] (f32) ----------------
__global__ __launch_bounds__(256) void transpose_w2_kernel(const float* __restrict__ W2,
                                                           float* __restrict__ W2T) {
    for (int i = threadIdx.x; i < NHID * NCLASS; i += 256) {
        int k = i / NCLASS, j = i - k * NCLASS;
        W2T[(size_t)j * NHID + k] = W2[i];
    }
}

// ---------------- gemm1 (MFMA fp16): suph = fp16( x @ W1 ), x converted inline ----
#define GM_BM 128
#define GM_BK 32

__global__ __launch_bounds__(256) void gemm1_mfma_kernel(const float* __restrict__ A,
                                                         const ushort* __restrict__ Bt,
                                                         ushort* __restrict__ Ch,
                                                         int M) {
    __shared__ ushort As[GM_BM * GM_BK];   // 8 KB, XOR-swizzled 16B slots
    __shared__ ushort Bs[GM_BM * GM_BK];   // 8 KB
    const int tid = threadIdx.x;
    const int wid = tid >> 6, lane = tid & 63;
    const int row0 = blockIdx.x * GM_BM;
    const int col0 = blockIdx.y * GM_BM;   // 0 or 128 (N=256)
    const int wr = (wid >> 1) * 64;
    const int wc = (wid & 1) * 64;
    const int l15 = lane & 15;
    const int lq  = lane >> 4;             // k-chunk 0..3

    const int sr = tid >> 2;               // staging row 0..63
    const int sc = tid & 3;                // staging 16B slot (8 fp16 / 32B f32)

    f32x4 acc[4][4] = {};

    for (int k0 = 0; k0 < NFEAT; k0 += GM_BK) {
        {
            int r0g = row0 + sr;
            int r1g = row0 + sr + 64;
            uint4 a0 = make_uint4(0, 0, 0, 0), a1 = make_uint4(0, 0, 0, 0);
            if (r0g < M) {
                const float4* p = reinterpret_cast<const float4*>(&A[(size_t)r0g * NFEAT + k0 + sc * 8]);
                a0 = pack8(p[0], p[1]);
            }
            if (r1g < M) {
                const float4* p = reinterpret_cast<const float4*>(&A[(size_t)r1g * NFEAT + k0 + sc * 8]);
                a1 = pack8(p[0], p[1]);
            }
            int sw0 = sc ^ ((sr ^ (sr >> 2)) & 3);
            int sw1 = sc ^ (((sr + 64) ^ ((sr + 64) >> 2)) & 3);
            *reinterpret_cast<uint4*>(&As[sr * GM_BK + sw0 * 8]) = a0;
            *reinterpret_cast<uint4*>(&As[(sr + 64) * GM_BK + sw1 * 8]) = a1;
            uint4 b0 = *reinterpret_cast<const uint4*>(&Bt[(size_t)(col0 + sr) * NFEAT + k0 + sc * 8]);
            uint4 b1v = *reinterpret_cast<const uint4*>(&Bt[(size_t)(col0 + sr + 64) * NFEAT + k0 + sc * 8]);
            *reinterpret_cast<uint4*>(&Bs[sr * GM_BK + sw0 * 8]) = b0;
            *reinterpret_cast<uint4*>(&Bs[(sr + 64) * GM_BK + sw1 * 8]) = b1v;
        }
        __syncthreads();
        f16x8 af[4], bfr[4];
        #pragma unroll
        for (int mi = 0; mi < 4; ++mi) {
            int r = wr + mi * 16 + l15;
            int sw = lq ^ ((r ^ (r >> 2)) & 3);
            af[mi] = *reinterpret_cast<const f16x8*>(&As[r * GM_BK + sw * 8]);
        }
        #pragma unroll
        for (int ni = 0; ni < 4; ++ni) {
            int c = wc + ni * 16 + l15;
            int sw = lq ^ ((c ^ (c >> 2)) & 3);
            bfr[ni] = *reinterpret_cast<const f16x8*>(&Bs[c * GM_BK + sw * 8]);
        }
        #pragma unroll
        for (int mi = 0; mi < 4; ++mi)
            #pragma unroll
            for (int ni = 0; ni < 4; ++ni)
                acc[mi][ni] = __builtin_amdgcn_mfma_f32_16x16x32_f16(af[mi], bfr[ni], acc[mi][ni], 0, 0, 0);
        __syncthreads();
    }
    // C/D layout: col = lane&15, row = (lane>>4)*4 + reg
    #pragma unroll
    for (int mi = 0; mi < 4; ++mi) {
        #pragma unroll
        for (int j = 0; j < 4; ++j) {
            int gr = row0 + wr + mi * 16 + lq * 4 + j;
            if (gr < M) {
                #pragma unroll
                for (int ni = 0; ni < 4; ++ni) {
                    Ch[(size_t)gr * NHID + col0 + wc + ni * 16 + l15] = f2h(acc[mi][ni][j]);
                }
            }
        }
    }
}

// ---------------- CSR build ----------------
__global__ __launch_bounds__(256) void hist_kernel(const int* __restrict__ dst,
                                                   int* __restrict__ deg, int E) {
    int e = blockIdx.x * 256 + threadIdx.x;
    if (e < E) atomicAdd(&deg[dst[e]], 1);
}

#define SCAN_CHUNK 1024
__global__ __launch_bounds__(256) void scan1_kernel(const int* __restrict__ deg,
                                                    int* __restrict__ part,
                                                    int* __restrict__ bsums, int N) {
    __shared__ int s[256];
    int b = blockIdx.x, t = threadIdx.x;
    int i0 = b * SCAN_CHUNK + t * 4;
    int d[4];
    #pragma unroll
    for (int u = 0; u < 4; ++u) d[u] = (i0 + u < N) ? deg[i0 + u] : 0;
    int loc = d[0] + d[1] + d[2] + d[3];
    s[t] = loc;
    __syncthreads();
    for (int off = 1; off < 256; off <<= 1) {
        int v = (t >= off) ? s[t - off] : 0;
        __syncthreads();
        s[t] += v;
        __syncthreads();
    }
    int run = s[t] - loc;
    #pragma unroll
    for (int u = 0; u < 4; ++u) {
        if (i0 + u < N) part[i0 + u] = run;
        run += d[u];
    }
    if (t == 255) bsums[b] = s[255];
}

__global__ __launch_bounds__(128) void scan2_kernel(int* __restrict__ bsums, int nb) {
    __shared__ int s[128];
    int t = threadIdx.x;
    int v = (t < nb) ? bsums[t] : 0;
    s[t] = v;
    __syncthreads();
    for (int off = 1; off < 128; off <<= 1) {
        int x = (t >= off) ? s[t - off] : 0;
        __syncthreads();
        s[t] += x;
        __syncthreads();
    }
    if (t < nb) bsums[t] = s[t] - v;
}

__global__ __launch_bounds__(256) void scan3_kernel(int* __restrict__ row_start,
                                                    const int* __restrict__ bsums,
                                                    int N, int E) {
    int b = blockIdx.x, t = threadIdx.x;
    int i0 = b * SCAN_CHUNK + t * 4;
    int add = bsums[b];
    #pragma unroll
    for (int u = 0; u < 4; ++u)
        if (i0 + u < N) row_start[i0 + u] += add;
    if (b == 0 && t == 0) row_start[N] = E;
}

__global__ __launch_bounds__(256) void scatter_kernel(const int* __restrict__ src,
                                                      const int* __restrict__ dst,
                                                      const float* __restrict__ w,
                                                      int* __restrict__ cursor,
                                                      int2* __restrict__ csr, int E) {
    int e = blockIdx.x * 256 + threadIdx.x;
    if (e >= E) return;
    int d = dst[e];
    int pos = atomicAdd(&cursor[d], 1);
    csr[pos] = make_int2(src[e], __float_as_int(w[e]));
}

// ---------------- conv1: c2[n] = relu( (A @ suph)[n] + b1 ) @ W2 ----------------
// ONE WAVE per node. Lanes 0-31: even edge of a pair; 32-63: odd edge.
// Lane owns 8 contiguous feats (16 B). Edge list loaded lane-parallel, pairs
// distributed via __shfl; 8 pairs (8 loads) in flight. No __syncthreads.
__global__ __launch_bounds__(256, 4) void conv1_kernel(const int2* __restrict__ csr,
                                                       const int* __restrict__ row_start,
                                                       const ushort* __restrict__ suph,
                                                       const float* __restrict__ b1,
                                                       const float* __restrict__ w2t,
                                                       float* __restrict__ c2, int N) {
    __shared__ float hrow[4][NHID];       // per-wave slice, 4 KB
    const int wave = threadIdx.x >> 6;
    const int lane = threadIdx.x & 63;
    const int half = lane >> 5;
    const int fl   = lane & 31;
    const int n = blockIdx.x * 4 + wave;
    if (n >= N) return;
    const int start = row_start[n], end = row_start[n + 1];

    float acc[8] = {};
    for (int c0 = start; c0 < end; c0 += 64) {
        int clen = min(64, end - c0);
        int2 eL = (lane < clen) ? csr[c0 + lane] : make_int2(0, 0);
        int npairs  = (clen + 1) >> 1;
        int npair8  = (npairs + 7) & ~7;         // pad; idx>=clen lanes hold {0,0}
        for (int t = 0; t < npair8; t += 8) {
            int   sidx[8];
            float wv[8];
            uint4 v[8];
            #pragma unroll
            for (int u = 0; u < 8; ++u) {
                int idx = 2 * (t + u) + half;    // <= 63 by construction
                sidx[u] = __shfl(eL.x, idx, 64);
                wv[u]   = __int_as_float(__shfl(eL.y, idx, 64));
            }
            #pragma unroll
            for (int u = 0; u < 8; ++u)
                v[u] = *reinterpret_cast<const uint4*>(&suph[(size_t)sidx[u] * NHID + fl * 8]);
            #pragma unroll
            for (int u = 0; u < 8; ++u) {
                acc[0] += wv[u] * hlo(v[u].x);
                acc[1] += wv[u] * hhi(v[u].x);
                acc[2] += wv[u] * hlo(v[u].y);
                acc[3] += wv[u] * hhi(v[u].y);
                acc[4] += wv[u] * hlo(v[u].z);
                acc[5] += wv[u] * hhi(v[u].z);
                acc[6] += wv[u] * hlo(v[u].w);
                acc[7] += wv[u] * hhi(v[u].w);
            }
        }
    }
    #pragma unroll
    for (int i = 0; i < 8; ++i) acc[i] += __shfl_xor(acc[i], 32, 64);
    if (half == 0) {
        float4 ba = *reinterpret_cast<const float4*>(&b1[fl * 8]);
        float4 bb = *reinterpret_cast<const float4*>(&b1[fl * 8 + 4]);
        *reinterpret_cast<float4*>(&hrow[wave][fl * 8]) =
            make_float4(fmaxf(acc[0] + ba.x, 0.f), fmaxf(acc[1] + ba.y, 0.f),
                        fmaxf(acc[2] + ba.z, 0.f), fmaxf(acc[3] + ba.w, 0.f));
        *reinterpret_cast<float4*>(&hrow[wave][fl * 8 + 4]) =
            make_float4(fmaxf(acc[4] + bb.x, 0.f), fmaxf(acc[5] + bb.y, 0.f),
                        fmaxf(acc[6] + bb.z, 0.f), fmaxf(acc[7] + bb.w, 0.f));
    }
    // wave-local epilogue (same wave wrote hrow[wave]; lgkmcnt orders it)
    if (lane < NCLASS) {
        const float4* wp = reinterpret_cast<const float4*>(&w2t[(size_t)lane * NHID]);
        const float4* hp = reinterpret_cast<const float4*>(&hrow[wave][0]);
        float p = 0.f;
        #pragma unroll 8
        for (int k4 = 0; k4 < 64; ++k4) {
            float4 h4 = hp[k4];
            float4 w4 = wp[k4];
            p += h4.x * w4.x + h4.y * w4.y + h4.z * w4.z + h4.w * w4.w;
        }
        c2[(size_t)n * NCLASS + lane] = p;
    }
}

// ---------------- conv2: out[n] = softmax( (A @ c2)[n] ) ----------------
// one wave per dst node; lanes 0..39 own classes; 16 edges in flight.
__global__ __launch_bounds__(256, 4) void conv2_kernel(const int2* __restrict__ csr,
                                                       const int* __restrict__ row_start,
                                                       const float* __restrict__ c2,
                                                       float* __restrict__ out, int N) {
    int wave = threadIdx.x >> 6;
    int lane = threadIdx.x & 63;
    int n = blockIdx.x * 4 + wave;
    if (n >= N) return;
    int start = row_start[n], end = row_start[n + 1];
    bool act = lane < NCLASS;
    float acc = 0.f;
    int j = start;
    for (; j + 15 < end; j += 16) {
        int2 ee[16];
        #pragma unroll
        for (int u = 0; u < 16; ++u) ee[u] = csr[j + u];
        if (act) {
            float sv[16];
            #pragma unroll
            for (int u = 0; u < 16; ++u) sv[u] = c2[(size_t)ee[u].x * NCLASS + lane];
            #pragma unroll
            for (int u = 0; u < 16; ++u) acc += __int_as_float(ee[u].y) * sv[u];
        }
    }
    for (; j + 3 < end; j += 4) {
        int2 ee[4];
        #pragma unroll
        for (int u = 0; u < 4; ++u) ee[u] = csr[j + u];
        if (act) {
            float sv[4];
            #pragma unroll
            for (int u = 0; u < 4; ++u) sv[u] = c2[(size_t)ee[u].x * NCLASS + lane];
            #pragma unroll
            for (int u = 0; u < 4; ++u) acc += __int_as_float(ee[u].y) * sv[u];
        }
    }
    for (; j < end; ++j) {
        int2 e0 = csr[j];
        if (act) acc += __int_as_float(e0.y) * c2[(size_t)e0.x * NCLASS + lane];
    }
    float m = act ? acc : -INFINITY;
    #pragma unroll
    for (int off = 32; off > 0; off >>= 1) m = fmaxf(m, __shfl_xor(m, off, 64));
    float e = act ? expf(acc - m) : 0.f;
    float s = e;
    #pragma unroll
    for (int off = 32; off > 0; off >>= 1) s += __shfl_xor(s, off, 64);
    if (act) out[(size_t)n * NCLASS + lane] = e / s;
}

extern "C" void kernel_launch(void* const* d_in, const int* in_sizes, int n_in,
                              void* d_out, int out_size, void* d_ws, size_t ws_size,
                              hipStream_t stream) {
    const float* x  = (const float*)d_in[0];
    const int*   ei = (const int*)d_in[1];
    const float* ew = (const float*)d_in[2];
    const float* W1 = (const float*)d_in[3];
    const float* b1 = (const float*)d_in[4];
    const float* W2 = (const float*)d_in[5];
    float* out = (float*)d_out;

    const int M = in_sizes[0] / NFEAT;       // 100000
    const int E = in_sizes[1] / 2;           // 3200000
    const int* src = ei;
    const int* dst = ei + E;

    // workspace layout (~94 MB)
    char* ws = (char*)d_ws;
    ushort* suph    = (ushort*)ws;                                  // M*256 fp16 = 51.2 MB
    float*  c2      = (float*)(suph + (size_t)M * NHID);            // M*40 f32   = 16 MB
    int2*   csr     = (int2*)(c2 + (size_t)M * NCLASS);             // E int2     = 25.6 MB
    int*    deg     = (int*)(csr + E);                              // M
    int*    row_start = deg + M;                                    // M+1
    int*    cursor  = row_start + (M + 1);                          // M
    int*    bsums   = cursor + M;                                   // 128
    float*  w2t     = (float*)(bsums + 128);                        // 40*256 f32
    ushort* w1t     = (ushort*)(w2t + NCLASS * NHID);               // 256*512 fp16

    const int nscan = (M + SCAN_CHUNK - 1) / SCAN_CHUNK;

    // ---- converts + CSR build ----
    convert_w1t_kernel<<<NFEAT, 256, 0, stream>>>(W1, w1t);
    transpose_w2_kernel<<<1, 256, 0, stream>>>(W2, w2t);

    hipMemsetAsync(deg, 0, (size_t)M * 4, stream);
    hist_kernel<<<(E + 255) / 256, 256, 0, stream>>>(dst, deg, E);
    scan1_kernel<<<nscan, 256, 0, stream>>>(deg, row_start, bsums, M);
    scan2_kernel<<<1, 128, 0, stream>>>(bsums, nscan);
    scan3_kernel<<<nscan, 256, 0, stream>>>(row_start, bsums, M, E);
    hipMemcpyAsync(cursor, row_start, (size_t)M * 4, hipMemcpyDeviceToDevice, stream);
    scatter_kernel<<<(E + 255) / 256, 256, 0, stream>>>(src, dst, ew, cursor, csr, E);

    // ---- dense + sparse pipeline ----
    dim3 g1((M + GM_BM - 1) / GM_BM, NHID / GM_BM);
    gemm1_mfma_kernel<<<g1, 256, 0, stream>>>(x, w1t, suph, M);

    conv1_kernel<<<(M + 3) / 4, 256, 0, stream>>>(csr, row_start, suph, b1, w2t, c2, M);
    conv2_kernel<<<(M + 3) / 4, 256, 0, stream>>>(csr, row_start, c2, out, M);
}